// Round 1
// baseline (2150.909 us; speedup 1.0000x reference)
//
#include <hip/hip_runtime.h>
#include <cstdint>

typedef unsigned short u16;
typedef float  f32x4  __attribute__((ext_vector_type(4)));
typedef short  short8 __attribute__((ext_vector_type(8)));
typedef u16    u16x8  __attribute__((ext_vector_type(8)));

__device__ inline float bf2f(u16 b){
  unsigned int u = ((unsigned int)b) << 16;
  float f; __builtin_memcpy(&f, &u, 4); return f;
}
__device__ inline u16 f2bf(float f){
  unsigned int u; __builtin_memcpy(&u, &f, 4);
  unsigned int r = u + 0x7FFFu + ((u >> 16) & 1u);
  return (u16)(r >> 16);
}
__device__ inline void gload_lds16(const void* g, void* l){
  __builtin_amdgcn_global_load_lds((const __attribute__((address_space(1))) unsigned int*)g,
                                   (__attribute__((address_space(3))) unsigned int*)l,
                                   16, 0, 0);
}

// ---------------------------------------------------------------------------
// prep: Wt_in[n][k]=bf16(W_in[k][n]); Wt_hd likewise; gW1[d][k][e]=g*W1; W2t[d][k][e]=W2[d][e][k]
// ---------------------------------------------------------------------------
__global__ __launch_bounds__(256) void prep_k(
    const float* __restrict__ W_in, const float* __restrict__ W_head,
    const float* __restrict__ ln_g, const float* __restrict__ W1,
    const float* __restrict__ W2,
    u16* __restrict__ Wt_in, u16* __restrict__ Wt_hd,
    float* __restrict__ gW1, float* __restrict__ W2t)
{
  int idx = blockIdx.x * 256 + threadIdx.x;
  if (idx < 262144){
    int n = idx >> 9, k = idx & 511;
    Wt_in[idx] = f2bf(W_in[k * 512 + n]);
  } else if (idx < 524288){
    int j = idx - 262144; int n = j >> 9, k = j & 511;
    Wt_hd[j] = f2bf(W_head[k * 512 + n]);
  } else if (idx < 540672){
    int j = idx - 524288;               // [8][512][4] flat
    int d = j >> 11; int r = j & 2047; int k = r >> 2;
    gW1[j] = ln_g[d * 512 + k] * W1[j];
  } else if (idx < 557056){
    int j = idx - 540672;
    int d = j >> 11; int r = j & 2047; int k = r >> 2, e = r & 3;
    W2t[j] = W2[(d * 4 + e) * 512 + k];
  }
}

// U[d][e] = sum_k g*W1 ; V[d][e] = sum_k ln_b*W1 + b1
__global__ __launch_bounds__(64) void uv_k(
    const float* __restrict__ ln_g, const float* __restrict__ ln_b,
    const float* __restrict__ W1, const float* __restrict__ b1,
    float* __restrict__ U, float* __restrict__ V)
{
  int d = blockIdx.x >> 2, e = blockIdx.x & 3;
  int lane = threadIdx.x;
  float u = 0.f, v = 0.f;
  for (int k = lane; k < 512; k += 64){
    float w = W1[(d * 512 + k) * 4 + e];
    u += ln_g[d * 512 + k] * w;
    v += ln_b[d * 512 + k] * w;
  }
  for (int m = 1; m < 64; m <<= 1){ u += __shfl_xor(u, m); v += __shfl_xor(v, m); }
  if (lane == 0){ U[d * 4 + e] = u; V[d * 4 + e] = v + b1[d * 4 + e]; }
}

// ---------------------------------------------------------------------------
// GEMM: C[M x 512] = A[M x 512] @ W[512 x 512], W given transposed bf16 (Wt[n][k]).
// BM=128, BN=128, BK=64, 256 threads (4 waves, 2x2), 16x16x32 bf16 MFMA.
// LDS tiles [128][64] bf16, XOR swizzle: chunk16B ^= (row&7).
// A_F32: A is f32 (reg-stage + convert); else bf16 via global_load_lds.
// RELU_BF16: epilogue relu + bf16 store (h); else f32 store (+bias both).
// ---------------------------------------------------------------------------
template<int A_F32, int RELU_BF16>
__global__ __launch_bounds__(256) void gemm_k(
    const void* __restrict__ Ap, const u16* __restrict__ Bt,
    const float* __restrict__ bias, void* __restrict__ Cp)
{
  __shared__ char lds[65536];   // A0:0 A1:16K B0:32K B1:48K
  const int tid  = threadIdx.x;
  const int lane = tid & 63;
  const int w    = tid >> 6;
  const int wm   = w >> 1, wn = w & 1;
  const int bn   = blockIdx.x, bm = blockIdx.y;

  f32x4 acc[4][4];
  #pragma unroll
  for (int i = 0; i < 4; i++)
    #pragma unroll
    for (int j = 0; j < 4; j++) acc[i][j] = (f32x4)0.f;

  // global_load_lds staging (B always; A when bf16)
  const int r8  = lane >> 3;
  const int pch = lane & 7;
  const int lch = pch ^ r8;                 // inverse-swizzled source chunk
  const u16* Bg = Bt + (size_t)(bn * 128 + w * 32 + r8) * 512 + lch * 8;
  const u16* Ag16 = (const u16*)Ap + (size_t)(bm * 128 + w * 32 + r8) * 512 + lch * 8;

  // f32 A reg staging
  const int arow = tid >> 3;                // 0..31
  const int alc  = tid & 7;
  const float* Ag32 = (const float*)Ap + (size_t)(bm * 128 + arow) * 512 + alc * 8;
  const int awoff = (alc ^ (arow & 7)) << 4;

  f32x4 areg[8];

  auto issueA32 = [&](int t){
    #pragma unroll
    for (int i = 0; i < 4; i++){
      const float* p = Ag32 + (size_t)i * 32 * 512 + t * 64;
      areg[2*i]   = *(const f32x4*)p;
      areg[2*i+1] = *(const f32x4*)(p + 4);
    }
  };
  auto writeA32 = [&](int buf){
    char* base = lds + buf * 16384;
    #pragma unroll
    for (int i = 0; i < 4; i++){
      f32x4 x0 = areg[2*i], x1 = areg[2*i+1];
      short8 v;
      v[0] = (short)f2bf(x0.x); v[1] = (short)f2bf(x0.y);
      v[2] = (short)f2bf(x0.z); v[3] = (short)f2bf(x0.w);
      v[4] = (short)f2bf(x1.x); v[5] = (short)f2bf(x1.y);
      v[6] = (short)f2bf(x1.z); v[7] = (short)f2bf(x1.w);
      *(short8*)(base + (i * 32 + arow) * 128 + awoff) = v;
    }
  };
  auto issueA16 = [&](int t, int buf){
    char* base = lds + buf * 16384 + (w * 32) * 128;
    const u16* g = Ag16 + t * 64;
    #pragma unroll
    for (int i = 0; i < 4; i++)
      gload_lds16(g + (size_t)i * 8 * 512, base + i * 1024);
  };
  auto issueB = [&](int t, int buf){
    char* base = lds + 32768 + buf * 16384 + (w * 32) * 128;
    const u16* g = Bg + t * 64;
    #pragma unroll
    for (int i = 0; i < 4; i++)
      gload_lds16(g + (size_t)i * 8 * 512, base + i * 1024);
  };

  const int l15 = lane & 15, gq = lane >> 4;
  const int cb0 = ((gq ^ (l15 & 7)) << 4);

  auto compute = [&](int buf){
    char* A_ = lds + buf * 16384;
    char* B_ = lds + 32768 + buf * 16384;
    #pragma unroll
    for (int ks = 0; ks < 2; ks++){
      const int cb = cb0 ^ (ks << 6);
      short8 af[4], bfr[4];
      #pragma unroll
      for (int f = 0; f < 4; f++)
        af[f] = *(const short8*)(A_ + (wm * 64 + f * 16 + l15) * 128 + cb);
      #pragma unroll
      for (int f = 0; f < 4; f++)
        bfr[f] = *(const short8*)(B_ + (wn * 64 + f * 16 + l15) * 128 + cb);
      #pragma unroll
      for (int i = 0; i < 4; i++)
        #pragma unroll
        for (int j = 0; j < 4; j++)
          acc[i][j] = __builtin_amdgcn_mfma_f32_16x16x32_bf16(af[i], bfr[j], acc[i][j], 0, 0, 0);
    }
  };

  // prologue
  if (A_F32) issueA32(0); else issueA16(0, 0);
  issueB(0, 0);
  if (A_F32) writeA32(0);
  __syncthreads();

  int cur = 0;
  #pragma unroll 1
  for (int t = 0; t < 8; t++){
    if (t < 7){
      if (A_F32) issueA32(t + 1); else issueA16(t + 1, cur ^ 1);
      issueB(t + 1, cur ^ 1);
    }
    compute(cur);
    if (t < 7){
      if (A_F32) writeA32(cur ^ 1);
      __syncthreads();
      cur ^= 1;
    }
  }

  // epilogue
  #pragma unroll
  for (int fn = 0; fn < 4; fn++){
    const int col = bn * 128 + wn * 64 + fn * 16 + l15;
    const float bv = bias[col];
    #pragma unroll
    for (int fm = 0; fm < 4; fm++){
      const int row0 = bm * 128 + wm * 64 + fm * 16 + gq * 4;
      #pragma unroll
      for (int r = 0; r < 4; r++){
        float v = acc[fm][fn][r] + bv;
        if (RELU_BF16){
          v = v > 0.f ? v : 0.f;
          ((u16*)Cp)[(size_t)(row0 + r) * 512 + col] = f2bf(v);
        } else {
          ((float*)Cp)[(size_t)(row0 + r) * 512 + col] = v;
        }
      }
    }
  }
}

// ---------------------------------------------------------------------------
// middle: 8 residual blocks, folded-LN. 8 lanes/row, 64 cols/lane in regs.
// z1[e] = relu(rs*(S[e]-mu*U[e]) + V[e]);  h += W2t·z1 + b2
// ---------------------------------------------------------------------------
__global__ __launch_bounds__(256) void mid_k(
    u16* __restrict__ h, const float* __restrict__ gW1,
    const float* __restrict__ W2t, const float* __restrict__ U,
    const float* __restrict__ V, const float* __restrict__ b2)
{
  const int tid = threadIdx.x;
  const int row = blockIdx.x * 32 + (tid >> 3);
  const int l   = tid & 7;
  u16* hr = h + (size_t)row * 512 + l * 8;

  float hv[64];
  #pragma unroll
  for (int i = 0; i < 8; i++){
    u16x8 v = *(const u16x8*)(hr + i * 64);
    #pragma unroll
    for (int j = 0; j < 8; j++) hv[i * 8 + j] = bf2f(v[j]);
  }

  #pragma unroll 1
  for (int d = 0; d < 8; d++){
    float s = 0.f, q = 0.f;
    #pragma unroll
    for (int t = 0; t < 64; t++){ s += hv[t]; q = fmaf(hv[t], hv[t], q); }
    s += __shfl_xor(s, 1); s += __shfl_xor(s, 2); s += __shfl_xor(s, 4);
    q += __shfl_xor(q, 1); q += __shfl_xor(q, 2); q += __shfl_xor(q, 4);
    const float mu  = s * (1.f / 512.f);
    const float var = q * (1.f / 512.f) - mu * mu;
    const float rs  = rsqrtf(var + 1e-5f);

    float S0 = 0.f, S1 = 0.f, S2 = 0.f, S3 = 0.f;
    const float* gw = gW1 + d * 2048 + l * 32;
    #pragma unroll
    for (int i = 0; i < 8; i++){
      #pragma unroll
      for (int j = 0; j < 8; j++){
        f32x4 g4 = *(const f32x4*)(gw + i * 256 + j * 4);
        float hvv = hv[i * 8 + j];
        S0 = fmaf(hvv, g4.x, S0); S1 = fmaf(hvv, g4.y, S1);
        S2 = fmaf(hvv, g4.z, S2); S3 = fmaf(hvv, g4.w, S3);
      }
    }
    S0 += __shfl_xor(S0, 1); S0 += __shfl_xor(S0, 2); S0 += __shfl_xor(S0, 4);
    S1 += __shfl_xor(S1, 1); S1 += __shfl_xor(S1, 2); S1 += __shfl_xor(S1, 4);
    S2 += __shfl_xor(S2, 1); S2 += __shfl_xor(S2, 2); S2 += __shfl_xor(S2, 4);
    S3 += __shfl_xor(S3, 1); S3 += __shfl_xor(S3, 2); S3 += __shfl_xor(S3, 4);

    float z0 = fmaf(rs, S0 - mu * U[d * 4 + 0], V[d * 4 + 0]); z0 = z0 > 0.f ? z0 : 0.f;
    float z1 = fmaf(rs, S1 - mu * U[d * 4 + 1], V[d * 4 + 1]); z1 = z1 > 0.f ? z1 : 0.f;
    float z2 = fmaf(rs, S2 - mu * U[d * 4 + 2], V[d * 4 + 2]); z2 = z2 > 0.f ? z2 : 0.f;
    float z3 = fmaf(rs, S3 - mu * U[d * 4 + 3], V[d * 4 + 3]); z3 = z3 > 0.f ? z3 : 0.f;

    const float* w2 = W2t + d * 2048 + l * 32;
    const float* bb = b2 + d * 512 + l * 8;
    #pragma unroll
    for (int i = 0; i < 8; i++){
      f32x4 ba0 = *(const f32x4*)(bb + i * 64);
      f32x4 ba1 = *(const f32x4*)(bb + i * 64 + 4);
      #pragma unroll
      for (int j = 0; j < 8; j++){
        f32x4 w4 = *(const f32x4*)(w2 + i * 256 + j * 4);
        float add = fmaf(z0, w4.x, fmaf(z1, w4.y, fmaf(z2, w4.z, z3 * w4.w)));
        float bj = (j < 4) ? ba0[j] : ba1[j - 4];
        hv[i * 8 + j] += add + bj;
      }
    }
  }

  #pragma unroll
  for (int i = 0; i < 8; i++){
    u16x8 v;
    #pragma unroll
    for (int j = 0; j < 8; j++) v[j] = f2bf(hv[i * 8 + j]);
    *(u16x8*)(hr + i * 64) = v;
  }
}

// ---------------------------------------------------------------------------
extern "C" void kernel_launch(void* const* d_in, const int* in_sizes, int n_in,
                              void* d_out, int out_size, void* d_ws, size_t ws_size,
                              hipStream_t stream)
{
  const float* x      = (const float*)d_in[0];
  const float* W_in   = (const float*)d_in[1];
  const float* b_in   = (const float*)d_in[2];
  const float* ln_g   = (const float*)d_in[3];
  const float* ln_b   = (const float*)d_in[4];
  const float* W1     = (const float*)d_in[5];
  const float* b1     = (const float*)d_in[6];
  const float* W2     = (const float*)d_in[7];
  const float* b2     = (const float*)d_in[8];
  const float* W_head = (const float*)d_in[9];
  const float* b_head = (const float*)d_in[10];
  float* out = (float*)d_out;
  const int B = in_sizes[0] / 512;

  char* ws = (char*)d_ws;
  size_t hbytes = (size_t)B * 512 * 2;
  u16*   h     = (u16*)ws;
  u16*   Wt_in = (u16*)(ws + hbytes);
  u16*   Wt_hd = Wt_in + 262144;
  float* gW1p  = (float*)(ws + hbytes + (size_t)2 * 262144 * 2);
  float* W2tp  = gW1p + 16384;
  float* Up    = W2tp + 16384;
  float* Vp    = Up + 32;

  prep_k<<<2176, 256, 0, stream>>>(W_in, W_head, ln_g, W1, W2, Wt_in, Wt_hd, gW1p, W2tp);
  uv_k<<<32, 64, 0, stream>>>(ln_g, ln_b, W1, b1, Up, Vp);
  gemm_k<1, 1><<<dim3(4, B / 128), 256, 0, stream>>>(x, Wt_in, b_in, h);
  mid_k<<<B / 32, 256, 0, stream>>>(h, gW1p, W2tp, Up, Vp, b2);
  gemm_k<0, 0><<<dim3(4, B / 128), 256, 0, stream>>>(h, Wt_hd, b_head, out);
}

// Round 2
// 592.255 us; speedup vs baseline: 3.6317x; 3.6317x over previous
//
#include <hip/hip_runtime.h>
#include <cstdint>

typedef unsigned short u16;
typedef float  f32x4  __attribute__((ext_vector_type(4)));
typedef short  short8 __attribute__((ext_vector_type(8)));
typedef u16    u16x8  __attribute__((ext_vector_type(8)));

__device__ inline float bf2f(u16 b){
  unsigned int u = ((unsigned int)b) << 16;
  float f; __builtin_memcpy(&f, &u, 4); return f;
}
__device__ inline u16 f2bf(float f){
  unsigned int u; __builtin_memcpy(&u, &f, 4);
  unsigned int r = u + 0x7FFFu + ((u >> 16) & 1u);
  return (u16)(r >> 16);
}
__device__ inline void gload_lds16(const void* g, void* l){
  __builtin_amdgcn_global_load_lds((const __attribute__((address_space(1))) unsigned int*)g,
                                   (__attribute__((address_space(3))) unsigned int*)l,
                                   16, 0, 0);
}

// ---------------------------------------------------------------------------
// prep:
//  Wt_in[n][k]=bf16(W_in[k][n]); Wt_hd likewise.
//  gW1s/W2ts/b2s: per-depth weight arrays PRE-PERMUTED so a linear LDS copy
//  yields a bank-conflict-free read pattern. Storage index p = j*32 + sl,
//  holding the entry for k = (sl ^ (j&7))*16 + j.
//   gW1s[d][p] = f32x4 { ln_g[d][k] * W1[d][k][e] }          (8KB/depth)
//   W2ts[d][p] = f32x4 { W2[d][e][k] }                       (8KB/depth)
//   b2s [d][p] = b2[d][k]                                    (2KB/depth)
// ---------------------------------------------------------------------------
__global__ __launch_bounds__(256) void prep_k(
    const float* __restrict__ W_in, const float* __restrict__ W_head,
    const float* __restrict__ ln_g, const float* __restrict__ W1,
    const float* __restrict__ W2, const float* __restrict__ b2,
    u16* __restrict__ Wt_in, u16* __restrict__ Wt_hd,
    f32x4* __restrict__ gW1s, f32x4* __restrict__ W2ts, float* __restrict__ b2s)
{
  int idx = blockIdx.x * 256 + threadIdx.x;
  if (idx < 262144){
    int n = idx >> 9, k = idx & 511;
    Wt_in[idx] = f2bf(W_in[k * 512 + n]);
  } else if (idx < 524288){
    int j = idx - 262144; int n = j >> 9, k = j & 511;
    Wt_hd[j] = f2bf(W_head[k * 512 + n]);
  } else if (idx < 528384){
    int t = idx - 524288;                 // [8][512] f32x4
    int d = t >> 9, p = t & 511;
    int j = p >> 5, sl = p & 31, s = sl ^ (j & 7);
    int k = s * 16 + j;
    float g = ln_g[d * 512 + k];
    f32x4 v;
    v.x = g * W1[(d * 512 + k) * 4 + 0];
    v.y = g * W1[(d * 512 + k) * 4 + 1];
    v.z = g * W1[(d * 512 + k) * 4 + 2];
    v.w = g * W1[(d * 512 + k) * 4 + 3];
    gW1s[t] = v;
  } else if (idx < 532480){
    int t = idx - 528384;
    int d = t >> 9, p = t & 511;
    int j = p >> 5, sl = p & 31, s = sl ^ (j & 7);
    int k = s * 16 + j;
    f32x4 v;
    v.x = W2[(d * 4 + 0) * 512 + k];
    v.y = W2[(d * 4 + 1) * 512 + k];
    v.z = W2[(d * 4 + 2) * 512 + k];
    v.w = W2[(d * 4 + 3) * 512 + k];
    W2ts[t] = v;
  } else if (idx < 536576){
    int t = idx - 532480;
    int d = t >> 9, p = t & 511;
    int j = p >> 5, sl = p & 31, s = sl ^ (j & 7);
    int k = s * 16 + j;
    b2s[t] = b2[d * 512 + k];
  }
}

// U[d][e] = sum_k g*W1 ; V[d][e] = sum_k ln_b*W1 + b1
__global__ __launch_bounds__(64) void uv_k(
    const float* __restrict__ ln_g, const float* __restrict__ ln_b,
    const float* __restrict__ W1, const float* __restrict__ b1,
    float* __restrict__ U, float* __restrict__ V)
{
  int d = blockIdx.x >> 2, e = blockIdx.x & 3;
  int lane = threadIdx.x;
  float u = 0.f, v = 0.f;
  for (int k = lane; k < 512; k += 64){
    float w = W1[(d * 512 + k) * 4 + e];
    u += ln_g[d * 512 + k] * w;
    v += ln_b[d * 512 + k] * w;
  }
  for (int m = 1; m < 64; m <<= 1){ u += __shfl_xor(u, m); v += __shfl_xor(v, m); }
  if (lane == 0){ U[d * 4 + e] = u; V[d * 4 + e] = v + b1[d * 4 + e]; }
}

// ---------------------------------------------------------------------------
// GEMM: C[M x 512] = A[M x 512] @ W[512 x 512], W given transposed bf16 (Wt[n][k]).
// (unchanged from round 1 — passing)
// ---------------------------------------------------------------------------
template<int A_F32, int RELU_BF16>
__global__ __launch_bounds__(256) void gemm_k(
    const void* __restrict__ Ap, const u16* __restrict__ Bt,
    const float* __restrict__ bias, void* __restrict__ Cp)
{
  __shared__ char lds[65536];   // A0:0 A1:16K B0:32K B1:48K
  const int tid  = threadIdx.x;
  const int lane = tid & 63;
  const int w    = tid >> 6;
  const int wm   = w >> 1, wn = w & 1;
  const int bn   = blockIdx.x, bm = blockIdx.y;

  f32x4 acc[4][4];
  #pragma unroll
  for (int i = 0; i < 4; i++)
    #pragma unroll
    for (int j = 0; j < 4; j++) acc[i][j] = (f32x4)0.f;

  const int r8  = lane >> 3;
  const int pch = lane & 7;
  const int lch = pch ^ r8;
  const u16* Bg = Bt + (size_t)(bn * 128 + w * 32 + r8) * 512 + lch * 8;
  const u16* Ag16 = (const u16*)Ap + (size_t)(bm * 128 + w * 32 + r8) * 512 + lch * 8;

  const int arow = tid >> 3;
  const int alc  = tid & 7;
  const float* Ag32 = (const float*)Ap + (size_t)(bm * 128 + arow) * 512 + alc * 8;
  const int awoff = (alc ^ (arow & 7)) << 4;

  f32x4 areg[8];

  auto issueA32 = [&](int t){
    #pragma unroll
    for (int i = 0; i < 4; i++){
      const float* p = Ag32 + (size_t)i * 32 * 512 + t * 64;
      areg[2*i]   = *(const f32x4*)p;
      areg[2*i+1] = *(const f32x4*)(p + 4);
    }
  };
  auto writeA32 = [&](int buf){
    char* base = lds + buf * 16384;
    #pragma unroll
    for (int i = 0; i < 4; i++){
      f32x4 x0 = areg[2*i], x1 = areg[2*i+1];
      short8 v;
      v[0] = (short)f2bf(x0.x); v[1] = (short)f2bf(x0.y);
      v[2] = (short)f2bf(x0.z); v[3] = (short)f2bf(x0.w);
      v[4] = (short)f2bf(x1.x); v[5] = (short)f2bf(x1.y);
      v[6] = (short)f2bf(x1.z); v[7] = (short)f2bf(x1.w);
      *(short8*)(base + (i * 32 + arow) * 128 + awoff) = v;
    }
  };
  auto issueA16 = [&](int t, int buf){
    char* base = lds + buf * 16384 + (w * 32) * 128;
    const u16* g = Ag16 + t * 64;
    #pragma unroll
    for (int i = 0; i < 4; i++)
      gload_lds16(g + (size_t)i * 8 * 512, base + i * 1024);
  };
  auto issueB = [&](int t, int buf){
    char* base = lds + 32768 + buf * 16384 + (w * 32) * 128;
    const u16* g = Bg + t * 64;
    #pragma unroll
    for (int i = 0; i < 4; i++)
      gload_lds16(g + (size_t)i * 8 * 512, base + i * 1024);
  };

  const int l15 = lane & 15, gq = lane >> 4;
  const int cb0 = ((gq ^ (l15 & 7)) << 4);

  auto compute = [&](int buf){
    char* A_ = lds + buf * 16384;
    char* B_ = lds + 32768 + buf * 16384;
    #pragma unroll
    for (int ks = 0; ks < 2; ks++){
      const int cb = cb0 ^ (ks << 6);
      short8 af[4], bfr[4];
      #pragma unroll
      for (int f = 0; f < 4; f++)
        af[f] = *(const short8*)(A_ + (wm * 64 + f * 16 + l15) * 128 + cb);
      #pragma unroll
      for (int f = 0; f < 4; f++)
        bfr[f] = *(const short8*)(B_ + (wn * 64 + f * 16 + l15) * 128 + cb);
      #pragma unroll
      for (int i = 0; i < 4; i++)
        #pragma unroll
        for (int j = 0; j < 4; j++)
          acc[i][j] = __builtin_amdgcn_mfma_f32_16x16x32_bf16(af[i], bfr[j], acc[i][j], 0, 0, 0);
    }
  };

  if (A_F32) issueA32(0); else issueA16(0, 0);
  issueB(0, 0);
  if (A_F32) writeA32(0);
  __syncthreads();

  int cur = 0;
  #pragma unroll 1
  for (int t = 0; t < 8; t++){
    if (t < 7){
      if (A_F32) issueA32(t + 1); else issueA16(t + 1, cur ^ 1);
      issueB(t + 1, cur ^ 1);
    }
    compute(cur);
    if (t < 7){
      if (A_F32) writeA32(cur ^ 1);
      __syncthreads();
      cur ^= 1;
    }
  }

  #pragma unroll
  for (int fn = 0; fn < 4; fn++){
    const int col = bn * 128 + wn * 64 + fn * 16 + l15;
    const float bv = bias[col];
    #pragma unroll
    for (int fm = 0; fm < 4; fm++){
      const int row0 = bm * 128 + wm * 64 + fm * 16 + gq * 4;
      #pragma unroll
      for (int r = 0; r < 4; r++){
        float v = acc[fm][fn][r] + bv;
        if (RELU_BF16){
          v = v > 0.f ? v : 0.f;
          ((u16*)Cp)[(size_t)(row0 + r) * 512 + col] = f2bf(v);
        } else {
          ((float*)Cp)[(size_t)(row0 + r) * 512 + col] = v;
        }
      }
    }
  }
}

// ---------------------------------------------------------------------------
// middle: 8 residual blocks, folded-LN. 32 lanes/row-group, 4 rows/thread,
// 16 k/lane. Weights staged per depth in LDS (double-buffered, async
// global_load_lds), swizzled layout p = j*32 + (s^(j&7)) -> conflict-free.
// ---------------------------------------------------------------------------
__global__ __launch_bounds__(256, 3) void mid_k(
    u16* __restrict__ h, const f32x4* __restrict__ gW1s,
    const f32x4* __restrict__ W2ts, const float* __restrict__ b2s,
    const float* __restrict__ U, const float* __restrict__ V)
{
  __shared__ f32x4 sW1[2][512];
  __shared__ f32x4 sW2[2][512];
  __shared__ float sB2[2][512];

  const int tid  = threadIdx.x;
  const int s    = tid & 31;          // k-slice id
  const int rg   = tid >> 5;          // row-group 0..7
  const int wv   = tid >> 6;          // wave 0..3
  const int lane = tid & 63;
  const int row0 = blockIdx.x * 32 + rg * 4;

  u16* hp = h + (size_t)row0 * 512 + s * 16;

  // h: 4 rows x 16 k in registers (f32 across all depths)
  float hv[4][16];
  #pragma unroll
  for (int r = 0; r < 4; r++){
    u16x8 a = *(const u16x8*)(hp + r * 512);
    u16x8 b = *(const u16x8*)(hp + r * 512 + 8);
    #pragma unroll
    for (int j = 0; j < 8; j++){ hv[r][j] = bf2f(a[j]); hv[r][8 + j] = bf2f(b[j]); }
  }

  auto stage = [&](int d, int buf){
    #pragma unroll
    for (int i = 0; i < 2; i++){
      gload_lds16(gW1s + d * 512 + (wv * 2 + i) * 64 + lane,
                  (char*)&sW1[buf][0] + (wv * 2 + i) * 1024);
      gload_lds16(W2ts + d * 512 + (wv * 2 + i) * 64 + lane,
                  (char*)&sW2[buf][0] + (wv * 2 + i) * 1024);
    }
    if (wv < 2)
      gload_lds16(b2s + d * 512 + wv * 256 + lane * 4,
                  (char*)&sB2[buf][0] + wv * 1024);
  };

  stage(0, 0);
  __syncthreads();

  int buf = 0;
  #pragma unroll 1
  for (int d = 0; d < 8; d++){
    if (d < 7) stage(d + 1, buf ^ 1);

    // ---- LN stats over the 4 rows
    float sm[4], sq[4];
    #pragma unroll
    for (int r = 0; r < 4; r++){
      float a = 0.f, q = 0.f;
      #pragma unroll
      for (int j = 0; j < 16; j++){ a += hv[r][j]; q = fmaf(hv[r][j], hv[r][j], q); }
      sm[r] = a; sq[r] = q;
    }
    #pragma unroll
    for (int m = 1; m < 32; m <<= 1){
      #pragma unroll
      for (int r = 0; r < 4; r++){ sm[r] += __shfl_xor(sm[r], m); sq[r] += __shfl_xor(sq[r], m); }
    }
    float mu[4], rs[4];
    #pragma unroll
    for (int r = 0; r < 4; r++){
      mu[r] = sm[r] * (1.f / 512.f);
      float var = sq[r] * (1.f / 512.f) - mu[r] * mu[r];
      rs[r] = rsqrtf(var + 1e-5f);
    }

    // ---- S[r][e] = sum_k h * (g .* W1)
    f32x4 S[4];
    #pragma unroll
    for (int r = 0; r < 4; r++) S[r] = (f32x4)0.f;
    #pragma unroll
    for (int j = 0; j < 16; j++){
      f32x4 wv4 = sW1[buf][j * 32 + (s ^ (j & 7))];
      #pragma unroll
      for (int r = 0; r < 4; r++){
        S[r].x = fmaf(hv[r][j], wv4.x, S[r].x);
        S[r].y = fmaf(hv[r][j], wv4.y, S[r].y);
        S[r].z = fmaf(hv[r][j], wv4.z, S[r].z);
        S[r].w = fmaf(hv[r][j], wv4.w, S[r].w);
      }
    }
    #pragma unroll
    for (int m = 1; m < 32; m <<= 1){
      #pragma unroll
      for (int r = 0; r < 4; r++){
        S[r].x += __shfl_xor(S[r].x, m);
        S[r].y += __shfl_xor(S[r].y, m);
        S[r].z += __shfl_xor(S[r].z, m);
        S[r].w += __shfl_xor(S[r].w, m);
      }
    }

    // ---- z = relu(rs*(S - mu*U) + V), in place in S
    const float U0 = U[d * 4 + 0], U1 = U[d * 4 + 1], U2 = U[d * 4 + 2], U3 = U[d * 4 + 3];
    const float V0 = V[d * 4 + 0], V1 = V[d * 4 + 1], V2 = V[d * 4 + 2], V3 = V[d * 4 + 3];
    #pragma unroll
    for (int r = 0; r < 4; r++){
      float z0 = fmaf(rs[r], S[r].x - mu[r] * U0, V0);
      float z1 = fmaf(rs[r], S[r].y - mu[r] * U1, V1);
      float z2 = fmaf(rs[r], S[r].z - mu[r] * U2, V2);
      float z3 = fmaf(rs[r], S[r].w - mu[r] * U3, V3);
      S[r].x = z0 > 0.f ? z0 : 0.f;
      S[r].y = z1 > 0.f ? z1 : 0.f;
      S[r].z = z2 > 0.f ? z2 : 0.f;
      S[r].w = z3 > 0.f ? z3 : 0.f;
    }

    // ---- h += z @ W2t + b2
    #pragma unroll
    for (int j = 0; j < 16; j++){
      const int p = j * 32 + (s ^ (j & 7));
      f32x4 w4 = sW2[buf][p];
      float bv = sB2[buf][p];
      #pragma unroll
      for (int r = 0; r < 4; r++){
        float add = fmaf(S[r].x, w4.x, fmaf(S[r].y, w4.y, fmaf(S[r].z, w4.z, S[r].w * w4.w)));
        hv[r][j] += add + bv;
      }
    }

    __syncthreads();     // drains prefetch (vmcnt) + protects buf reuse
    buf ^= 1;
  }

  #pragma unroll
  for (int r = 0; r < 4; r++){
    u16x8 a, b;
    #pragma unroll
    for (int j = 0; j < 8; j++){ a[j] = f2bf(hv[r][j]); b[j] = f2bf(hv[r][8 + j]); }
    *(u16x8*)(hp + r * 512) = a;
    *(u16x8*)(hp + r * 512 + 8) = b;
  }
}

// ---------------------------------------------------------------------------
extern "C" void kernel_launch(void* const* d_in, const int* in_sizes, int n_in,
                              void* d_out, int out_size, void* d_ws, size_t ws_size,
                              hipStream_t stream)
{
  const float* x      = (const float*)d_in[0];
  const float* W_in   = (const float*)d_in[1];
  const float* b_in   = (const float*)d_in[2];
  const float* ln_g   = (const float*)d_in[3];
  const float* ln_b   = (const float*)d_in[4];
  const float* W1     = (const float*)d_in[5];
  const float* b1     = (const float*)d_in[6];
  const float* W2     = (const float*)d_in[7];
  const float* b2     = (const float*)d_in[8];
  const float* W_head = (const float*)d_in[9];
  const float* b_head = (const float*)d_in[10];
  float* out = (float*)d_out;
  const int B = in_sizes[0] / 512;

  char* ws = (char*)d_ws;
  size_t hbytes = (size_t)B * 512 * 2;
  u16*   h     = (u16*)ws;
  u16*   Wt_in = (u16*)(ws + hbytes);
  u16*   Wt_hd = Wt_in + 262144;
  f32x4* gW1s  = (f32x4*)(ws + hbytes + (size_t)2 * 262144 * 2);
  f32x4* W2ts  = gW1s + 4096;
  float* b2s   = (float*)(W2ts + 4096);
  float* Up    = b2s + 4096;
  float* Vp    = Up + 32;

  prep_k<<<2096, 256, 0, stream>>>(W_in, W_head, ln_g, W1, W2, b2, Wt_in, Wt_hd, gW1s, W2ts, b2s);
  uv_k<<<32, 64, 0, stream>>>(ln_g, ln_b, W1, b1, Up, Vp);
  gemm_k<1, 1><<<dim3(4, B / 128), 256, 0, stream>>>(x, Wt_in, b_in, h);
  mid_k<<<B / 32, 256, 0, stream>>>(h, gW1s, W2ts, b2s, Up, Vp);
  gemm_k<0, 0><<<dim3(4, B / 128), 256, 0, stream>>>(h, Wt_hd, b_head, out);
}

// Round 3
// 516.380 us; speedup vs baseline: 4.1654x; 1.1469x over previous
//
#include <hip/hip_runtime.h>
#include <cstdint>
#include <string.h>

typedef unsigned short u16;
typedef unsigned int   u32;
typedef float  f32x4  __attribute__((ext_vector_type(4)));
typedef short  short8 __attribute__((ext_vector_type(8)));
typedef u16    u16x8  __attribute__((ext_vector_type(8)));
typedef u16    u16x4  __attribute__((ext_vector_type(4)));

__device__ inline float bf2f(u16 b){
  u32 u = ((u32)b) << 16;
  float f; __builtin_memcpy(&f, &u, 4); return f;
}
__device__ inline u16 f2bf(float f){
  u32 u; __builtin_memcpy(&u, &f, 4);
  u32 r = u + 0x7FFFu + ((u >> 16) & 1u);
  return (u16)(r >> 16);
}
// pack hi16(lo), hi16(hi) -> (bf16(lo) | bf16(hi)<<16), truncation (internal use only)
__device__ inline u32 pk(float hi, float lo){
  u32 a, b; __builtin_memcpy(&a, &hi, 4); __builtin_memcpy(&b, &lo, 4);
  return __builtin_amdgcn_perm(a, b, 0x07060302u);
}
__device__ inline void gload_lds16(const void* g, void* l){
  __builtin_amdgcn_global_load_lds((const __attribute__((address_space(1))) unsigned int*)g,
                                   (__attribute__((address_space(3))) unsigned int*)l,
                                   16, 0, 0);
}

// ---------------------------------------------------------------------------
// prep:
//  Wt_in[n][k]=bf16(W_in[k][n]); Wt_hd likewise.
//  gw1f: S-MFMA B-frags  [8d][16c][4g][5col][8i] bf16 (2560/depth)
//        value(col<4) = bf16(ln_g*W1[k][col]), col4 = 1.0; k = 32c + (i<4?4g+i:12+4g+i)
//  updA: update A-frags  [8d][32t][16m][8sl] bf16 (4096/depth)
//        k=16t+m; sl<4: W2[d][sl][k], sl4: b2[d][k], else 0
// ---------------------------------------------------------------------------
__global__ __launch_bounds__(256) void prep_k(
    const float* __restrict__ W_in, const float* __restrict__ W_head,
    const float* __restrict__ ln_g, const float* __restrict__ W1,
    const float* __restrict__ W2, const float* __restrict__ b2,
    u16* __restrict__ Wt_in, u16* __restrict__ Wt_hd,
    u16* __restrict__ gw1f, u16* __restrict__ updA)
{
  int idx = blockIdx.x * 256 + threadIdx.x;
  if (idx < 262144){
    int n = idx >> 9, k = idx & 511;
    Wt_in[idx] = f2bf(W_in[k * 512 + n]);
  } else if (idx < 524288){
    int j = idx - 262144; int n = j >> 9, k = j & 511;
    Wt_hd[j] = f2bf(W_head[k * 512 + n]);
  } else if (idx < 544768){
    int q = idx - 524288;                 // 8*2560
    int d = q / 2560, r = q % 2560;
    int c = r / 160, r2 = r % 160;
    int g = r2 / 40, r3 = r2 % 40;
    int col = r3 >> 3, i = r3 & 7;
    int k = 32 * c + (i < 4 ? 4 * g + i : 12 + 4 * g + i);
    u16 v;
    if (col == 4) v = 0x3F80u;
    else          v = f2bf(ln_g[d * 512 + k] * W1[(d * 512 + k) * 4 + col]);
    gw1f[q] = v;
  } else if (idx < 577536){
    int q = idx - 544768;                 // 8*4096
    int d = q >> 12, r = q & 4095;
    int t = r >> 7, r2 = r & 127;
    int m = r2 >> 3, sl = r2 & 7;
    int k = 16 * t + m;
    u16 v = 0;
    if (sl < 4)      v = f2bf(W2[(d * 4 + sl) * 512 + k]);
    else if (sl == 4) v = f2bf(b2[d * 512 + k]);
    updA[q] = v;
  }
}

// U[d][e] = sum_k bf16(g*W1) (consistent with MFMA's bf16 weights); V = sum ln_b*W1 + b1
__global__ __launch_bounds__(64) void uv_k(
    const float* __restrict__ ln_g, const float* __restrict__ ln_b,
    const float* __restrict__ W1, const float* __restrict__ b1,
    float* __restrict__ U, float* __restrict__ V)
{
  int d = blockIdx.x >> 2, e = blockIdx.x & 3;
  int lane = threadIdx.x;
  float u = 0.f, v = 0.f;
  for (int k = lane; k < 512; k += 64){
    float w = W1[(d * 512 + k) * 4 + e];
    u += bf2f(f2bf(ln_g[d * 512 + k] * w));
    v += ln_b[d * 512 + k] * w;
  }
  for (int m = 1; m < 64; m <<= 1){ u += __shfl_xor(u, m); v += __shfl_xor(v, m); }
  if (lane == 0){ U[d * 4 + e] = u; V[d * 4 + e] = v + b1[d * 4 + e]; }
}

// ---------------------------------------------------------------------------
// GEMM (unchanged, passing): C[M x 512] = A[M x 512] @ W, Wt[n][k] bf16.
// ---------------------------------------------------------------------------
template<int A_F32, int RELU_BF16>
__global__ __launch_bounds__(256) void gemm_k(
    const void* __restrict__ Ap, const u16* __restrict__ Bt,
    const float* __restrict__ bias, void* __restrict__ Cp)
{
  __shared__ char lds[65536];
  const int tid  = threadIdx.x;
  const int lane = tid & 63;
  const int w    = tid >> 6;
  const int wm   = w >> 1, wn = w & 1;
  const int bn   = blockIdx.x, bm = blockIdx.y;

  f32x4 acc[4][4];
  #pragma unroll
  for (int i = 0; i < 4; i++)
    #pragma unroll
    for (int j = 0; j < 4; j++) acc[i][j] = (f32x4)0.f;

  const int r8  = lane >> 3;
  const int pch = lane & 7;
  const int lch = pch ^ r8;
  const u16* Bg = Bt + (size_t)(bn * 128 + w * 32 + r8) * 512 + lch * 8;
  const u16* Ag16 = (const u16*)Ap + (size_t)(bm * 128 + w * 32 + r8) * 512 + lch * 8;

  const int arow = tid >> 3;
  const int alc  = tid & 7;
  const float* Ag32 = (const float*)Ap + (size_t)(bm * 128 + arow) * 512 + alc * 8;
  const int awoff = (alc ^ (arow & 7)) << 4;

  f32x4 areg[8];

  auto issueA32 = [&](int t){
    #pragma unroll
    for (int i = 0; i < 4; i++){
      const float* p = Ag32 + (size_t)i * 32 * 512 + t * 64;
      areg[2*i]   = *(const f32x4*)p;
      areg[2*i+1] = *(const f32x4*)(p + 4);
    }
  };
  auto writeA32 = [&](int buf){
    char* base = lds + buf * 16384;
    #pragma unroll
    for (int i = 0; i < 4; i++){
      f32x4 x0 = areg[2*i], x1 = areg[2*i+1];
      short8 v;
      v[0] = (short)f2bf(x0[0]); v[1] = (short)f2bf(x0[1]);
      v[2] = (short)f2bf(x0[2]); v[3] = (short)f2bf(x0[3]);
      v[4] = (short)f2bf(x1[0]); v[5] = (short)f2bf(x1[1]);
      v[6] = (short)f2bf(x1[2]); v[7] = (short)f2bf(x1[3]);
      *(short8*)(base + (i * 32 + arow) * 128 + awoff) = v;
    }
  };
  auto issueA16 = [&](int t, int buf){
    char* base = lds + buf * 16384 + (w * 32) * 128;
    const u16* g = Ag16 + t * 64;
    #pragma unroll
    for (int i = 0; i < 4; i++)
      gload_lds16(g + (size_t)i * 8 * 512, base + i * 1024);
  };
  auto issueB = [&](int t, int buf){
    char* base = lds + 32768 + buf * 16384 + (w * 32) * 128;
    const u16* g = Bg + t * 64;
    #pragma unroll
    for (int i = 0; i < 4; i++)
      gload_lds16(g + (size_t)i * 8 * 512, base + i * 1024);
  };

  const int l15 = lane & 15, gq = lane >> 4;
  const int cb0 = ((gq ^ (l15 & 7)) << 4);

  auto compute = [&](int buf){
    char* A_ = lds + buf * 16384;
    char* B_ = lds + 32768 + buf * 16384;
    #pragma unroll
    for (int ks = 0; ks < 2; ks++){
      const int cb = cb0 ^ (ks << 6);
      short8 af[4], bfr[4];
      #pragma unroll
      for (int f = 0; f < 4; f++)
        af[f] = *(const short8*)(A_ + (wm * 64 + f * 16 + l15) * 128 + cb);
      #pragma unroll
      for (int f = 0; f < 4; f++)
        bfr[f] = *(const short8*)(B_ + (wn * 64 + f * 16 + l15) * 128 + cb);
      #pragma unroll
      for (int i = 0; i < 4; i++)
        #pragma unroll
        for (int j = 0; j < 4; j++)
          acc[i][j] = __builtin_amdgcn_mfma_f32_16x16x32_bf16(af[i], bfr[j], acc[i][j], 0, 0, 0);
    }
  };

  if (A_F32) issueA32(0); else issueA16(0, 0);
  issueB(0, 0);
  if (A_F32) writeA32(0);
  __syncthreads();

  int cur = 0;
  #pragma unroll 1
  for (int t = 0; t < 8; t++){
    if (t < 7){
      if (A_F32) issueA32(t + 1); else issueA16(t + 1, cur ^ 1);
      issueB(t + 1, cur ^ 1);
    }
    compute(cur);
    if (t < 7){
      if (A_F32) writeA32(cur ^ 1);
      __syncthreads();
      cur ^= 1;
    }
  }

  #pragma unroll
  for (int fn = 0; fn < 4; fn++){
    const int col = bn * 128 + wn * 64 + fn * 16 + l15;
    const float bv = bias[col];
    #pragma unroll
    for (int fm = 0; fm < 4; fm++){
      const int row0 = bm * 128 + wm * 64 + fm * 16 + gq * 4;
      #pragma unroll
      for (int r = 0; r < 4; r++){
        float v = acc[fm][fn][r] + bv;
        if (RELU_BF16){
          v = v > 0.f ? v : 0.f;
          ((u16*)Cp)[(size_t)(row0 + r) * 512 + col] = f2bf(v);
        } else {
          ((float*)Cp)[(size_t)(row0 + r) * 512 + col] = v;
        }
      }
    }
  }
}

// ---------------------------------------------------------------------------
// mid v3: full-MFMA residual blocks. 1 wave = 16 rows, 512 k.
// lane: m=lane&15 (row / C-col role), g=lane>>4.
// h slots: hv[c][half][reg] = h[m][k], k = 32c + 16*half + 4g + reg  (f32, persistent)
// Per depth: S/sum = 16x mfma(h~, [gW1|1]); sumsq = 16x Gram mfma(h~,h~);
//            z via tiny LDS bounce; h = 32x mfma([W2|b2], [z|1], C=h).
// ---------------------------------------------------------------------------
__global__ __launch_bounds__(256) void mid_k(
    u16* __restrict__ h, const u16* __restrict__ gw1f,
    const u16* __restrict__ updA,
    const float* __restrict__ U, const float* __restrict__ V)
{
  __shared__ __align__(16) u16   sG[2][2560];
  __shared__ __align__(16) u16   sA[2][4096];
  __shared__ __align__(16) float sRed[4][96];   // per wave: sum[16], ssq[16], z[16][4]
  __shared__ __align__(16) float sUV[64];       // U[32], V[32]
  __shared__ __align__(16) u16   sZ[8];         // 16B zero page

  const int tid  = threadIdx.x;
  const int wv   = tid >> 6;
  const int lane = tid & 63;
  const int m    = lane & 15;
  const int g    = lane >> 4;
  const int row  = blockIdx.x * 64 + wv * 16 + m;

  if (tid < 8) sZ[tid] = 0;
  if (tid >= 64 && tid < 96)  sUV[tid - 64]      = U[tid - 64];
  if (tid >= 96 && tid < 128) sUV[tid - 96 + 32] = V[tid - 96];

  // ---- load h (f32 regs, 128/lane)
  u16* hrow = h + (size_t)row * 512;
  f32x4 hv[16][2];
  #pragma unroll
  for (int c = 0; c < 16; c++){
    u16x4 a = *(const u16x4*)(hrow + 32 * c + 4 * g);
    u16x4 b = *(const u16x4*)(hrow + 32 * c + 16 + 4 * g);
    #pragma unroll
    for (int r = 0; r < 4; r++){ hv[c][0][r] = bf2f(a[r]); hv[c][1][r] = bf2f(b[r]); }
  }

  auto stage = [&](int d, int buf){
    const char* gs = (const char*)(gw1f + d * 2560);
    char* dsg = (char*)&sG[buf][0];
    gload_lds16(gs + wv * 1024 + lane * 16, dsg + wv * 1024);
    if (wv == 0) gload_lds16(gs + 4096 + lane * 16, dsg + 4096);
    const char* as = (const char*)(updA + d * 4096);
    char* dsa = (char*)&sA[buf][0];
    gload_lds16(as + wv * 1024 + lane * 16, dsa + wv * 1024);
    gload_lds16(as + 4096 + wv * 1024 + lane * 16, dsa + 4096 + wv * 1024);
  };

  stage(0, 0);
  __syncthreads();

  int buf = 0;
  #pragma unroll 1
  for (int d = 0; d < 8; d++){
    if (d < 7) stage(d + 1, buf ^ 1);

    // ---- S + sum (ones col) + Gram(sumsq)
    const u16* gb = (m < 5) ? &sG[buf][g * 40 + m * 8] : &sZ[0];
    const int ginc = (m < 5) ? 160 : 0;

    f32x4 aS = {0.f, 0.f, 0.f, 0.f}, aG = {0.f, 0.f, 0.f, 0.f};
    #pragma unroll
    for (int c = 0; c < 16; c++){
      union { u32 u[4]; short8 s; } af;
      af.u[0] = pk(hv[c][0][1], hv[c][0][0]);
      af.u[1] = pk(hv[c][0][3], hv[c][0][2]);
      af.u[2] = pk(hv[c][1][1], hv[c][1][0]);
      af.u[3] = pk(hv[c][1][3], hv[c][1][2]);
      short8 bf = *(const short8*)(gb + c * ginc);
      aS = __builtin_amdgcn_mfma_f32_16x16x32_bf16(af.s, bf,   aS, 0, 0, 0);
      aG = __builtin_amdgcn_mfma_f32_16x16x32_bf16(af.s, af.s, aG, 0, 0, 0);
    }

    // ---- stats bounce (wave-internal LDS, no barrier)
    if (m == 4) *(f32x4*)&sRed[wv][4 * g] = aS;           // sum[4g+r]
    if ((m >> 2) == g){                                    // Gram diagonal
      int r = m & 3;
      float dv = (r == 0) ? aG[0] : (r == 1) ? aG[1] : (r == 2) ? aG[2] : aG[3];
      sRed[wv][16 + m] = dv;
    }
    f32x4 sum4 = *(const f32x4*)&sRed[wv][4 * g];
    f32x4 ssq4 = *(const f32x4*)&sRed[wv][16 + 4 * g];

    const float Uc = sUV[d * 4 + (m & 3)];
    const float Vc = sUV[32 + d * 4 + (m & 3)];
    f32x4 zw;
    #pragma unroll
    for (int r = 0; r < 4; r++){
      float mu  = sum4[r] * (1.f / 512.f);
      float var = ssq4[r] * (1.f / 512.f) - mu * mu;
      float rs  = rsqrtf(var + 1e-5f);
      float z   = fmaf(rs, aS[r] - mu * Uc, Vc);
      zw[r] = z > 0.f ? z : 0.f;
    }
    if (m < 4){
      sRed[wv][32 + (4 * g + 0) * 4 + m] = zw[0];
      sRed[wv][32 + (4 * g + 1) * 4 + m] = zw[1];
      sRed[wv][32 + (4 * g + 2) * 4 + m] = zw[2];
      sRed[wv][32 + (4 * g + 3) * 4 + m] = zw[3];
    }
    f32x4 z4 = *(const f32x4*)&sRed[wv][32 + m * 4];       // z[m][0..3]

    // ---- update: h += [W2|b2]^T [z|1]
    union { u32 u[4]; short8 s; } bz;
    bz.u[0] = (g == 0) ? pk(z4[1], z4[0]) : 0u;
    bz.u[1] = (g == 0) ? pk(z4[3], z4[2]) : 0u;
    bz.u[2] = (g == 0) ? 0x00003F80u : 0u;
    bz.u[3] = 0u;

    const u16* ab = (g == 0) ? &sA[buf][m * 8] : &sZ[0];
    const int ainc = (g == 0) ? 128 : 0;
    #pragma unroll
    for (int t = 0; t < 32; t++){
      short8 aw = *(const short8*)(ab + t * ainc);
      hv[t >> 1][t & 1] =
        __builtin_amdgcn_mfma_f32_16x16x32_bf16(aw, bz.s, hv[t >> 1][t & 1], 0, 0, 0);
    }

    __syncthreads();
    buf ^= 1;
  }

  // ---- store h (RNE — this rounding feeds the head GEMM directly)
  #pragma unroll
  for (int c = 0; c < 16; c++){
    uint2 v0, v1;
    v0.x = (u32)f2bf(hv[c][0][0]) | ((u32)f2bf(hv[c][0][1]) << 16);
    v0.y = (u32)f2bf(hv[c][0][2]) | ((u32)f2bf(hv[c][0][3]) << 16);
    v1.x = (u32)f2bf(hv[c][1][0]) | ((u32)f2bf(hv[c][1][1]) << 16);
    v1.y = (u32)f2bf(hv[c][1][2]) | ((u32)f2bf(hv[c][1][3]) << 16);
    *(uint2*)(hrow + 32 * c + 4 * g)      = v0;
    *(uint2*)(hrow + 32 * c + 16 + 4 * g) = v1;
  }
}

// ---------------------------------------------------------------------------
extern "C" void kernel_launch(void* const* d_in, const int* in_sizes, int n_in,
                              void* d_out, int out_size, void* d_ws, size_t ws_size,
                              hipStream_t stream)
{
  const float* x      = (const float*)d_in[0];
  const float* W_in   = (const float*)d_in[1];
  const float* b_in   = (const float*)d_in[2];
  const float* ln_g   = (const float*)d_in[3];
  const float* ln_b   = (const float*)d_in[4];
  const float* W1     = (const float*)d_in[5];
  const float* b1     = (const float*)d_in[6];
  const float* W2     = (const float*)d_in[7];
  const float* b2     = (const float*)d_in[8];
  const float* W_head = (const float*)d_in[9];
  const float* b_head = (const float*)d_in[10];
  float* out = (float*)d_out;
  const int B = in_sizes[0] / 512;

  char* ws = (char*)d_ws;
  size_t hbytes = (size_t)B * 512 * 2;
  u16*   h     = (u16*)ws;
  u16*   Wt_in = (u16*)(ws + hbytes);
  u16*   Wt_hd = Wt_in + 262144;
  u16*   gw1f  = (u16*)(ws + hbytes + 1048576);
  u16*   updA  = gw1f + 20480;
  float* Up    = (float*)(ws + hbytes + 1048576 + 40960 + 65536);
  float* Vp    = Up + 32;

  prep_k<<<2256, 256, 0, stream>>>(W_in, W_head, ln_g, W1, W2, b2, Wt_in, Wt_hd, gw1f, updA);
  uv_k<<<32, 64, 0, stream>>>(ln_g, ln_b, W1, b1, Up, Vp);
  gemm_k<1, 1><<<dim3(4, B / 128), 256, 0, stream>>>(x, Wt_in, b_in, h);
  mid_k<<<B / 64, 256, 0, stream>>>(h, gw1f, updA, Up, Vp);
  gemm_k<0, 0><<<dim3(4, B / 128), 256, 0, stream>>>(h, Wt_hd, b_head, out);
}

// Round 4
// 496.334 us; speedup vs baseline: 4.3336x; 1.0404x over previous
//
#include <hip/hip_runtime.h>
#include <cstdint>

typedef unsigned short u16;
typedef unsigned int   u32;
typedef float  f32x4  __attribute__((ext_vector_type(4)));
typedef short  short8 __attribute__((ext_vector_type(8)));

__device__ inline float bf2f(u16 b){ u32 u=((u32)b)<<16; float f; __builtin_memcpy(&f,&u,4); return f; }
__device__ inline u16 f2bf(float f){ u32 u; __builtin_memcpy(&u,&f,4); u32 r=u+0x7FFFu+((u>>16)&1u); return (u16)(r>>16); }
// truncating pack (exact when inputs are already bf16-valued)
__device__ inline u32 pk(float hi, float lo){ u32 a,b; __builtin_memcpy(&a,&hi,4); __builtin_memcpy(&b,&lo,4); return __builtin_amdgcn_perm(a,b,0x07060302u); }
// RNE pack
__device__ inline u32 pkr(float hi, float lo){ return (u32)f2bf(lo) | ((u32)f2bf(hi)<<16); }
__device__ inline void gload_lds16(const void* g, void* l){
  __builtin_amdgcn_global_load_lds((const __attribute__((address_space(1))) unsigned int*)g,
                                   (__attribute__((address_space(3))) unsigned int*)l, 16, 0, 0);
}

// ---------------------------------------------------------------------------
// prep:
//  Wt_in[n][k] = bf16(W_in[k][n])                              (512x512)
//  Wt_hd2[n][32t + slot] = bf16(W_head[k][n]), slot=8g+i,
//        k = 32t + (i<4 ? 4g+i : 12+4g+i)   (sigma-permuted for hv frags)
//  gw1f: S-MFMA B-frags  [8d][16c][4g][5col][8i] bf16 (2560/depth)
//  updA: update A-frags  [8d][32t][16m][8sl] bf16 (4096/depth)
// ---------------------------------------------------------------------------
__global__ __launch_bounds__(256) void prep_k(
    const float* __restrict__ W_in, const float* __restrict__ W_head,
    const float* __restrict__ ln_g, const float* __restrict__ W1,
    const float* __restrict__ W2, const float* __restrict__ b2,
    u16* __restrict__ Wt_in, u16* __restrict__ Wt_hd2,
    u16* __restrict__ gw1f, u16* __restrict__ updA)
{
  int idx = blockIdx.x * 256 + threadIdx.x;
  if (idx < 262144){
    int n = idx >> 9, k = idx & 511;
    Wt_in[idx] = f2bf(W_in[k * 512 + n]);
  } else if (idx < 524288){
    int j = idx - 262144; int n = j >> 9, kk = j & 511;
    int t = kk >> 5, sl = kk & 31, gg = sl >> 3, ii = sl & 7;
    int k = 32 * t + (ii < 4 ? 4 * gg + ii : 12 + 4 * gg + ii);
    Wt_hd2[j] = f2bf(W_head[k * 512 + n]);
  } else if (idx < 544768){
    int q = idx - 524288;                 // 8*2560
    int d = q / 2560, r = q % 2560;
    int c = r / 160, r2 = r % 160;
    int g = r2 / 40, r3 = r2 % 40;
    int col = r3 >> 3, i = r3 & 7;
    int k = 32 * c + (i < 4 ? 4 * g + i : 12 + 4 * g + i);
    u16 v;
    if (col == 4) v = 0x3F80u;
    else          v = f2bf(ln_g[d * 512 + k] * W1[(d * 512 + k) * 4 + col]);
    gw1f[q] = v;
  } else if (idx < 577536){
    int q = idx - 544768;                 // 8*4096
    int d = q >> 12, r = q & 4095;
    int t = r >> 7, r2 = r & 127;
    int m = r2 >> 3, sl = r2 & 7;
    int k = 16 * t + m;
    u16 v = 0;
    if (sl < 4)       v = f2bf(W2[(d * 4 + sl) * 512 + k]);
    else if (sl == 4) v = f2bf(b2[d * 512 + k]);
    updA[q] = v;
  }
}

// U[d][e] = sum_k bf16(g*W1) (consistent with MFMA weights); V = sum ln_b*W1 + b1
__global__ __launch_bounds__(64) void uv_k(
    const float* __restrict__ ln_g, const float* __restrict__ ln_b,
    const float* __restrict__ W1, const float* __restrict__ b1,
    float* __restrict__ U, float* __restrict__ V)
{
  int d = blockIdx.x >> 2, e = blockIdx.x & 3;
  int lane = threadIdx.x;
  float u = 0.f, v = 0.f;
  for (int k = lane; k < 512; k += 64){
    float w = W1[(d * 512 + k) * 4 + e];
    u += bf2f(f2bf(ln_g[d * 512 + k] * w));
    v += ln_b[d * 512 + k] * w;
  }
  for (int m = 1; m < 64; m <<= 1){ u += __shfl_xor(u, m); v += __shfl_xor(v, m); }
  if (lane == 0){ U[d * 4 + e] = u; V[d * 4 + e] = v + b1[d * 4 + e]; }
}

// ---------------------------------------------------------------------------
// fused: input GEMM -> 8 residual MLP blocks -> head GEMM, h never leaves regs.
// Block = 64 rows, 4 waves, 16 rows/wave. lane: m=lane&15 (batch), g=lane>>4.
// hv[c][half][r] = h[batch=m][k = 32c + 16*half + 4g + r]  (f32 persistent)
// LDS arena LT: phase A/C weight k-tiles [512 n][4x16B chunks, pos=chunk^(n&3)],
// double-buffered at LT+0 / LT+32768; mid weights overlap at LT+buf*16384.
// ---------------------------------------------------------------------------
__global__ __launch_bounds__(256) void fused_k(
    const float* __restrict__ x, const u16* __restrict__ Wt_in,
    const float* __restrict__ b_in, const u16* __restrict__ Wt_hd2,
    const float* __restrict__ b_head, const u16* __restrict__ gw1f,
    const u16* __restrict__ updA, const float* __restrict__ U,
    const float* __restrict__ V, float* __restrict__ out)
{
  __shared__ __align__(16) char  LT[65536];
  __shared__ __align__(16) float sRed[4][96];
  __shared__ __align__(16) float sUV[64];
  __shared__ __align__(16) u16   sZ[8];

  const int tid  = threadIdx.x;
  const int wv   = tid >> 6;
  const int lane = tid & 63;
  const int m    = lane & 15;
  const int g    = lane >> 4;
  const size_t row = (size_t)blockIdx.x * 64 + wv * 16 + m;

  if (tid < 8) sZ[tid] = 0;
  if (tid >= 64 && tid < 96)  sUV[tid - 64]      = U[tid - 64];
  if (tid >= 96 && tid < 128) sUV[tid - 96 + 32] = V[tid - 96];

  // stage one [512 n][32 k] bf16 tile of W (32KB) into LT+buf*32768
  auto stageT = [&](const u16* W, int t, int buf){
    char* dst = LT + buf * 32768 + tid * 16;
    const char* src = (const char*)W + t * 64;
    #pragma unroll
    for (int j = 0; j < 8; j++){
      int id = j * 256 + tid;
      int n = id >> 2, p = id & 3;
      gload_lds16(src + n * 1024 + ((p ^ (n & 3)) << 4), dst + j * 4096);
    }
  };
  // stage mid weights for depth d into LT+buf*16384 (sG 5120B + sA 8192B)
  auto stageM = [&](int d, int buf){
    char* dsg = LT + buf * 16384;
    char* dsa = dsg + 5120;
    const char* gs = (const char*)(gw1f + d * 2560);
    gload_lds16(gs + wv * 1024 + lane * 16, dsg + wv * 1024);
    if (wv == 0) gload_lds16(gs + 4096 + lane * 16, dsg + 4096);
    const char* as = (const char*)(updA + d * 4096);
    gload_lds16(as + wv * 1024 + lane * 16, dsa + wv * 1024);
    gload_lds16(as + 4096 + wv * 1024 + lane * 16, dsa + 4096 + wv * 1024);
  };

  // A-frag byte base inside a tile buffer: row m of n-tile, swizzled chunk
  const int afoff = m * 64 + ((g ^ (m & 3)) << 4);

  // ================= phase A: h = relu(x @ W_in + b_in) =================
  f32x4 hv[16][2];
  #pragma unroll
  for (int c = 0; c < 16; c++){ hv[c][0] = (f32x4)0.f; hv[c][1] = (f32x4)0.f; }

  const float* xp = x + row * 512 + g * 8;
  f32x4 xa[2], xb[2];
  xa[0] = *(const f32x4*)(xp);       xb[0] = *(const f32x4*)(xp + 4);
  xa[1] = *(const f32x4*)(xp + 32);  xb[1] = *(const f32x4*)(xp + 36);
  stageT(Wt_in, 0, 0);
  __syncthreads();

  #pragma unroll 2
  for (int t = 0; t < 16; t++){
    const int pb = t & 1;
    if (t < 15) stageT(Wt_in, t + 1, (t + 1) & 1); else stageM(0, 0);
    union { u32 u[4]; short8 s; } bx;
    bx.u[0] = pkr(xa[pb][1], xa[pb][0]);
    bx.u[1] = pkr(xa[pb][3], xa[pb][2]);
    bx.u[2] = pkr(xb[pb][1], xb[pb][0]);
    bx.u[3] = pkr(xb[pb][3], xb[pb][2]);
    if (t < 14){
      xa[pb] = *(const f32x4*)(xp + (t + 2) * 32);
      xb[pb] = *(const f32x4*)(xp + (t + 2) * 32 + 4);
    }
    const char* base = LT + pb * 32768 + afoff;
    #pragma unroll
    for (int nt = 0; nt < 32; nt++){
      short8 aw = *(const short8*)(base + nt * 1024);
      hv[nt >> 1][nt & 1] =
        __builtin_amdgcn_mfma_f32_16x16x32_bf16(aw, bx.s, hv[nt >> 1][nt & 1], 0, 0, 0);
    }
    __syncthreads();
  }

  // epilogue: +bias, relu, round to bf16 values (matches 3-kernel pipeline)
  #pragma unroll
  for (int c = 0; c < 16; c++){
    #pragma unroll
    for (int hf = 0; hf < 2; hf++){
      f32x4 bi = *(const f32x4*)(b_in + c * 32 + hf * 16 + g * 4);
      #pragma unroll
      for (int r = 0; r < 4; r++){
        float v = hv[c][hf][r] + bi[r];
        v = v > 0.f ? v : 0.f;
        hv[c][hf][r] = bf2f(f2bf(v));
      }
    }
  }

  // ================= mid: 8 residual MLP blocks (verbatim logic) ==========
  int mbuf = 0;
  #pragma unroll 1
  for (int d = 0; d < 8; d++){
    if (d < 7) stageM(d + 1, mbuf ^ 1); else stageT(Wt_hd2, 0, 1);

    const u16* sGp = (const u16*)(LT + mbuf * 16384);
    const u16* sAp = sGp + 2560;

    // ---- S + sum (ones col) + Gram(sumsq)
    const u16* gb = (m < 5) ? (sGp + g * 40 + m * 8) : &sZ[0];
    const int ginc = (m < 5) ? 160 : 0;

    f32x4 aS = {0.f, 0.f, 0.f, 0.f}, aG = {0.f, 0.f, 0.f, 0.f};
    #pragma unroll
    for (int c = 0; c < 16; c++){
      union { u32 u[4]; short8 s; } af;
      af.u[0] = pk(hv[c][0][1], hv[c][0][0]);
      af.u[1] = pk(hv[c][0][3], hv[c][0][2]);
      af.u[2] = pk(hv[c][1][1], hv[c][1][0]);
      af.u[3] = pk(hv[c][1][3], hv[c][1][2]);
      short8 bf = *(const short8*)(gb + c * ginc);
      aS = __builtin_amdgcn_mfma_f32_16x16x32_bf16(af.s, bf,   aS, 0, 0, 0);
      aG = __builtin_amdgcn_mfma_f32_16x16x32_bf16(af.s, af.s, aG, 0, 0, 0);
    }

    // ---- stats bounce (wave-internal LDS)
    if (m == 4) *(f32x4*)&sRed[wv][4 * g] = aS;
    if ((m >> 2) == g){
      int r = m & 3;
      float dv = (r == 0) ? aG[0] : (r == 1) ? aG[1] : (r == 2) ? aG[2] : aG[3];
      sRed[wv][16 + m] = dv;
    }
    f32x4 sum4 = *(const f32x4*)&sRed[wv][4 * g];
    f32x4 ssq4 = *(const f32x4*)&sRed[wv][16 + 4 * g];

    const float Uc = sUV[d * 4 + (m & 3)];
    const float Vc = sUV[32 + d * 4 + (m & 3)];
    f32x4 zw;
    #pragma unroll
    for (int r = 0; r < 4; r++){
      float mu  = sum4[r] * (1.f / 512.f);
      float var = ssq4[r] * (1.f / 512.f) - mu * mu;
      float rs  = rsqrtf(var + 1e-5f);
      float z   = fmaf(rs, aS[r] - mu * Uc, Vc);
      zw[r] = z > 0.f ? z : 0.f;
    }
    if (m < 4){
      sRed[wv][32 + (4 * g + 0) * 4 + m] = zw[0];
      sRed[wv][32 + (4 * g + 1) * 4 + m] = zw[1];
      sRed[wv][32 + (4 * g + 2) * 4 + m] = zw[2];
      sRed[wv][32 + (4 * g + 3) * 4 + m] = zw[3];
    }
    f32x4 z4 = *(const f32x4*)&sRed[wv][32 + m * 4];

    // ---- update: h += [W2|b2]^T [z|1]
    union { u32 u[4]; short8 s; } bz;
    bz.u[0] = (g == 0) ? pk(z4[1], z4[0]) : 0u;
    bz.u[1] = (g == 0) ? pk(z4[3], z4[2]) : 0u;
    bz.u[2] = (g == 0) ? 0x00003F80u : 0u;
    bz.u[3] = 0u;

    const u16* ab = (g == 0) ? (sAp + m * 8) : &sZ[0];
    const int ainc = (g == 0) ? 128 : 0;
    #pragma unroll
    for (int t2 = 0; t2 < 32; t2++){
      short8 aw = *(const short8*)(ab + t2 * ainc);
      hv[t2 >> 1][t2 & 1] =
        __builtin_amdgcn_mfma_f32_16x16x32_bf16(aw, bz.s, hv[t2 >> 1][t2 & 1], 0, 0, 0);
    }

    __syncthreads();
    mbuf ^= 1;
  }

  // ================= phase C: out = h @ W_head + b_head ===================
  // pack h to bf16 frags (RNE — this is the pipeline's h rounding)
  u32 hpk[16][4];
  #pragma unroll
  for (int c = 0; c < 16; c++){
    hpk[c][0] = pkr(hv[c][0][1], hv[c][0][0]);
    hpk[c][1] = pkr(hv[c][0][3], hv[c][0][2]);
    hpk[c][2] = pkr(hv[c][1][1], hv[c][1][0]);
    hpk[c][3] = pkr(hv[c][1][3], hv[c][1][2]);
  }

  f32x4 acc[32];
  #pragma unroll
  for (int nt = 0; nt < 32; nt++) acc[nt] = (f32x4)0.f;

  // tile t lives in buf (t+1)&1 (t0 staged into buf1 during mid d==7)
  #pragma unroll
  for (int t = 0; t < 16; t++){
    if (t < 15) stageT(Wt_hd2, t + 1, t & 1);
    union { u32 u[4]; short8 s; } bz;
    bz.u[0] = hpk[t][0]; bz.u[1] = hpk[t][1];
    bz.u[2] = hpk[t][2]; bz.u[3] = hpk[t][3];
    const char* base = LT + (((t + 1) & 1) * 32768) + afoff;
    #pragma unroll
    for (int nt = 0; nt < 32; nt++){
      short8 aw = *(const short8*)(base + nt * 1024);
      acc[nt] = __builtin_amdgcn_mfma_f32_16x16x32_bf16(aw, bz.s, acc[nt], 0, 0, 0);
    }
    __syncthreads();
  }

  float* op = out + row * 512 + g * 4;
  #pragma unroll
  for (int nt = 0; nt < 32; nt++){
    f32x4 bh = *(const f32x4*)(b_head + nt * 16 + g * 4);
    f32x4 v;
    #pragma unroll
    for (int r = 0; r < 4; r++) v[r] = acc[nt][r] + bh[r];
    *(f32x4*)(op + nt * 16) = v;
  }
}

// ---------------------------------------------------------------------------
extern "C" void kernel_launch(void* const* d_in, const int* in_sizes, int n_in,
                              void* d_out, int out_size, void* d_ws, size_t ws_size,
                              hipStream_t stream)
{
  const float* x      = (const float*)d_in[0];
  const float* W_in   = (const float*)d_in[1];
  const float* b_in   = (const float*)d_in[2];
  const float* ln_g   = (const float*)d_in[3];
  const float* ln_b   = (const float*)d_in[4];
  const float* W1     = (const float*)d_in[5];
  const float* b1     = (const float*)d_in[6];
  const float* W2     = (const float*)d_in[7];
  const float* b2     = (const float*)d_in[8];
  const float* W_head = (const float*)d_in[9];
  const float* b_head = (const float*)d_in[10];
  float* out = (float*)d_out;
  const int B = in_sizes[0] / 512;

  char* ws = (char*)d_ws;
  u16*   Wt_in  = (u16*)ws;                 // 262144
  u16*   Wt_hd2 = Wt_in + 262144;           // 262144
  u16*   gw1f   = Wt_hd2 + 262144;          // 20480
  u16*   updA   = gw1f + 20480;             // 32768
  float* Up     = (float*)(updA + 32768);   // 32
  float* Vp     = Up + 32;                  // 32

  prep_k<<<2256, 256, 0, stream>>>(W_in, W_head, ln_g, W1, W2, b2, Wt_in, Wt_hd2, gw1f, updA);
  uv_k<<<32, 64, 0, stream>>>(ln_g, ln_b, W1, b1, Up, Vp);
  fused_k<<<B / 64, 256, 0, stream>>>(x, Wt_in, b_in, Wt_hd2, b_head, gw1f, updA, Up, Vp, out);
}

// Round 5
// 472.979 us; speedup vs baseline: 4.5476x; 1.0494x over previous
//
#include <hip/hip_runtime.h>
#include <cstdint>

typedef unsigned short u16;
typedef unsigned int   u32;
typedef float  f32x4  __attribute__((ext_vector_type(4)));
typedef short  short8 __attribute__((ext_vector_type(8)));

__device__ inline float bf2f(u16 b){ u32 u=((u32)b)<<16; float f; __builtin_memcpy(&f,&u,4); return f; }
__device__ inline u16 f2bf(float f){ u32 u; __builtin_memcpy(&u,&f,4); u32 r=u+0x7FFFu+((u>>16)&1u); return (u16)(r>>16); }
// truncating pack (exact when inputs are already bf16-valued)
__device__ inline u32 pk(float hi, float lo){ u32 a,b; __builtin_memcpy(&a,&hi,4); __builtin_memcpy(&b,&lo,4); return __builtin_amdgcn_perm(a,b,0x07060302u); }
// RNE pack
__device__ inline u32 pkr(float hi, float lo){ return (u32)f2bf(lo) | ((u32)f2bf(hi)<<16); }
__device__ inline void gload_lds16(const void* g, void* l){
  __builtin_amdgcn_global_load_lds((const __attribute__((address_space(1))) unsigned int*)g,
                                   (__attribute__((address_space(3))) unsigned int*)l, 16, 0, 0);
}

// ---------------------------------------------------------------------------
// prep — emits weights in STAGED ORDER (the exact LDS tile image):
//  tile t (of 16, 32 k each) = 16384 u16 = 256 lines x 128B.
//  decode of u16 offset o: line=o>>6, w=o&63, slot=w>>3, i=w&7,
//    c8 = slot ^ (line&7), n = 2*line + (c8>>2), g = c8&3.
//  Wt_in3 value = bf16(W_in[k][n]),  k = t*32 + g*8 + i
//  Wt_hd3 value = bf16(W_head[k][n]), k = t*32 + (i<4 ? 4g+i : 12+4g+i)
//    (sigma-permutation matching hv fragment k-order)
//  gw1f: S-MFMA B-frags [8d][16c][4g][5col][8i] (2560/depth)
//  updA: update A-frags [8d][32t][16m][8sl]     (4096/depth)
// ---------------------------------------------------------------------------
__global__ __launch_bounds__(256) void prep_k(
    const float* __restrict__ W_in, const float* __restrict__ W_head,
    const float* __restrict__ ln_g, const float* __restrict__ W1,
    const float* __restrict__ W2, const float* __restrict__ b2,
    u16* __restrict__ Wt_in3, u16* __restrict__ Wt_hd3,
    u16* __restrict__ gw1f, u16* __restrict__ updA)
{
  int idx = blockIdx.x * 256 + threadIdx.x;
  if (idx < 524288){
    int which = idx >> 18;            // 0: W_in, 1: W_head
    int q = idx & 262143;
    int t = q >> 14, o = q & 16383;
    int line = o >> 6, w = o & 63, slot = w >> 3, i = w & 7;
    int c8 = slot ^ (line & 7);
    int n = 2 * line + (c8 >> 2);
    int g = c8 & 3;
    if (which == 0){
      int k = t * 32 + g * 8 + i;
      Wt_in3[q] = f2bf(W_in[k * 512 + n]);
    } else {
      int k = t * 32 + (i < 4 ? 4 * g + i : 12 + 4 * g + i);
      Wt_hd3[q] = f2bf(W_head[k * 512 + n]);
    }
  } else if (idx < 544768){
    int q = idx - 524288;                 // 8*2560
    int d = q / 2560, r = q % 2560;
    int c = r / 160, r2 = r % 160;
    int g = r2 / 40, r3 = r2 % 40;
    int col = r3 >> 3, i = r3 & 7;
    int k = 32 * c + (i < 4 ? 4 * g + i : 12 + 4 * g + i);
    u16 v;
    if (col == 4) v = 0x3F80u;
    else          v = f2bf(ln_g[d * 512 + k] * W1[(d * 512 + k) * 4 + col]);
    gw1f[q] = v;
  } else if (idx < 577536){
    int q = idx - 544768;                 // 8*4096
    int d = q >> 12, r = q & 4095;
    int t = r >> 7, r2 = r & 127;
    int m = r2 >> 3, sl = r2 & 7;
    int k = 16 * t + m;
    u16 v = 0;
    if (sl < 4)       v = f2bf(W2[(d * 4 + sl) * 512 + k]);
    else if (sl == 4) v = f2bf(b2[d * 512 + k]);
    updA[q] = v;
  }
}

// U[d][e] = sum_k bf16(g*W1) (consistent with MFMA weights); V = sum ln_b*W1 + b1
__global__ __launch_bounds__(64) void uv_k(
    const float* __restrict__ ln_g, const float* __restrict__ ln_b,
    const float* __restrict__ W1, const float* __restrict__ b1,
    float* __restrict__ U, float* __restrict__ V)
{
  int d = blockIdx.x >> 2, e = blockIdx.x & 3;
  int lane = threadIdx.x;
  float u = 0.f, v = 0.f;
  for (int k = lane; k < 512; k += 64){
    float w = W1[(d * 512 + k) * 4 + e];
    u += bf2f(f2bf(ln_g[d * 512 + k] * w));
    v += ln_b[d * 512 + k] * w;
  }
  for (int m = 1; m < 64; m <<= 1){ u += __shfl_xor(u, m); v += __shfl_xor(v, m); }
  if (lane == 0){ U[d * 4 + e] = u; V[d * 4 + e] = v + b1[d * 4 + e]; }
}

// ---------------------------------------------------------------------------
// fused: input GEMM -> 8 residual MLP blocks -> head GEMM, h never leaves regs.
// Block = 64 rows, 4 waves, 16 rows/wave. lane: m=lane&15 (batch), g=lane>>4.
// hv[c][half][r] = h[batch=m][k = 32c + 16*half + 4g + r]  (f32 persistent)
// Weight tiles are staged as a LINEAR copy of the pre-permuted staged-order
// arrays; A-frag read offset = (m>>1)*128 + ((((m&1)<<2)|g) ^ ((m>>1)&7))*16
// + nt*1024  -> all 8 bank-slots per quarter-wave, 2 lanes each (free).
// ---------------------------------------------------------------------------
__global__ __launch_bounds__(256) void fused_k(
    const float* __restrict__ x, const u16* __restrict__ Wt_in3,
    const float* __restrict__ b_in, const u16* __restrict__ Wt_hd3,
    const float* __restrict__ b_head, const u16* __restrict__ gw1f,
    const u16* __restrict__ updA, const float* __restrict__ U,
    const float* __restrict__ V, float* __restrict__ out)
{
  __shared__ __align__(16) char  LT[65536];
  __shared__ __align__(16) float sRed[4][96];
  __shared__ __align__(16) float sUV[64];
  __shared__ __align__(16) u16   sZ[8];

  const int tid  = threadIdx.x;
  const int wv   = tid >> 6;
  const int lane = tid & 63;
  const int m    = lane & 15;
  const int g    = lane >> 4;
  const size_t row = (size_t)blockIdx.x * 64 + wv * 16 + m;

  if (tid < 8) sZ[tid] = 0;
  if (tid >= 64 && tid < 96)  sUV[tid - 64]      = U[tid - 64];
  if (tid >= 96 && tid < 128) sUV[tid - 96 + 32] = V[tid - 96];

  // stage one 32KB staged-order tile (linear copy) into LT+buf*32768
  auto stageT = [&](const u16* W, int t, int buf){
    char* dst = LT + buf * 32768 + tid * 16;
    const char* src = (const char*)(W + t * 16384) + tid * 16;
    #pragma unroll
    for (int j = 0; j < 8; j++)
      gload_lds16(src + j * 4096, dst + j * 4096);
  };
  // stage mid weights for depth d into LT+buf*16384 (sG 5120B + sA 8192B)
  auto stageM = [&](int d, int buf){
    char* dsg = LT + buf * 16384;
    char* dsa = dsg + 5120;
    const char* gs = (const char*)(gw1f + d * 2560);
    gload_lds16(gs + wv * 1024 + lane * 16, dsg + wv * 1024);
    if (wv == 0) gload_lds16(gs + 4096 + lane * 16, dsg + 4096);
    const char* as = (const char*)(updA + d * 4096);
    gload_lds16(as + wv * 1024 + lane * 16, dsa + wv * 1024);
    gload_lds16(as + 4096 + wv * 1024 + lane * 16, dsa + 4096 + wv * 1024);
  };

  // A-frag byte base: line (m>>1), slot swizzled, step 1024/frag
  const int afoff = (m >> 1) * 128 + (((((m & 1) << 2) | g) ^ ((m >> 1) & 7)) << 4);

  // ================= phase A: h = relu(x @ W_in + b_in) =================
  f32x4 hv[16][2];
  #pragma unroll
  for (int c = 0; c < 16; c++){ hv[c][0] = (f32x4)0.f; hv[c][1] = (f32x4)0.f; }

  const float* xp = x + row * 512 + g * 8;
  f32x4 xa[2], xb[2];
  xa[0] = *(const f32x4*)(xp);       xb[0] = *(const f32x4*)(xp + 4);
  xa[1] = *(const f32x4*)(xp + 32);  xb[1] = *(const f32x4*)(xp + 36);
  stageT(Wt_in3, 0, 0);
  __syncthreads();

  #pragma unroll 2
  for (int t = 0; t < 16; t++){
    const int pb = t & 1;
    if (t < 15) stageT(Wt_in3, t + 1, (t + 1) & 1); else stageM(0, 0);
    union { u32 u[4]; short8 s; } bx;
    bx.u[0] = pkr(xa[pb][1], xa[pb][0]);
    bx.u[1] = pkr(xa[pb][3], xa[pb][2]);
    bx.u[2] = pkr(xb[pb][1], xb[pb][0]);
    bx.u[3] = pkr(xb[pb][3], xb[pb][2]);
    if (t < 14){
      xa[pb] = *(const f32x4*)(xp + (t + 2) * 32);
      xb[pb] = *(const f32x4*)(xp + (t + 2) * 32 + 4);
    }
    const char* base = LT + pb * 32768 + afoff;
    #pragma unroll
    for (int nt = 0; nt < 32; nt++){
      short8 aw = *(const short8*)(base + nt * 1024);
      hv[nt >> 1][nt & 1] =
        __builtin_amdgcn_mfma_f32_16x16x32_bf16(aw, bx.s, hv[nt >> 1][nt & 1], 0, 0, 0);
    }
    __syncthreads();
  }

  // epilogue: +bias, relu, round to bf16 values
  #pragma unroll
  for (int c = 0; c < 16; c++){
    #pragma unroll
    for (int hf = 0; hf < 2; hf++){
      f32x4 bi = *(const f32x4*)(b_in + c * 32 + hf * 16 + g * 4);
      #pragma unroll
      for (int r = 0; r < 4; r++){
        float v = hv[c][hf][r] + bi[r];
        v = v > 0.f ? v : 0.f;
        hv[c][hf][r] = bf2f(f2bf(v));
      }
    }
  }

  // ================= mid: 8 residual MLP blocks ==========
  int mbuf = 0;
  #pragma unroll 1
  for (int d = 0; d < 8; d++){
    if (d < 7) stageM(d + 1, mbuf ^ 1); else stageT(Wt_hd3, 0, 1);

    const u16* sGp = (const u16*)(LT + mbuf * 16384);
    const u16* sAp = sGp + 2560;

    // ---- S + sum (ones col) + Gram(sumsq), 2-way split chains
    const u16* gb = (m < 5) ? (sGp + g * 40 + m * 8) : &sZ[0];
    const int ginc = (m < 5) ? 160 : 0;

    f32x4 aSa[2] = {{0.f,0.f,0.f,0.f},{0.f,0.f,0.f,0.f}};
    f32x4 aGa[2] = {{0.f,0.f,0.f,0.f},{0.f,0.f,0.f,0.f}};
    #pragma unroll
    for (int c = 0; c < 16; c++){
      union { u32 u[4]; short8 s; } af;
      af.u[0] = pk(hv[c][0][1], hv[c][0][0]);
      af.u[1] = pk(hv[c][0][3], hv[c][0][2]);
      af.u[2] = pk(hv[c][1][1], hv[c][1][0]);
      af.u[3] = pk(hv[c][1][3], hv[c][1][2]);
      short8 bf = *(const short8*)(gb + c * ginc);
      aSa[c & 1] = __builtin_amdgcn_mfma_f32_16x16x32_bf16(af.s, bf,   aSa[c & 1], 0, 0, 0);
      aGa[c & 1] = __builtin_amdgcn_mfma_f32_16x16x32_bf16(af.s, af.s, aGa[c & 1], 0, 0, 0);
    }
    f32x4 aS = aSa[0] + aSa[1];
    f32x4 aG = aGa[0] + aGa[1];

    // ---- stats bounce (wave-internal LDS)
    if (m == 4) *(f32x4*)&sRed[wv][4 * g] = aS;
    if ((m >> 2) == g){
      int r = m & 3;
      float dv = (r == 0) ? aG[0] : (r == 1) ? aG[1] : (r == 2) ? aG[2] : aG[3];
      sRed[wv][16 + m] = dv;
    }
    f32x4 sum4 = *(const f32x4*)&sRed[wv][4 * g];
    f32x4 ssq4 = *(const f32x4*)&sRed[wv][16 + 4 * g];

    const float Uc = sUV[d * 4 + (m & 3)];
    const float Vc = sUV[32 + d * 4 + (m & 3)];
    f32x4 zw;
    #pragma unroll
    for (int r = 0; r < 4; r++){
      float mu  = sum4[r] * (1.f / 512.f);
      float var = ssq4[r] * (1.f / 512.f) - mu * mu;
      float rs  = rsqrtf(var + 1e-5f);
      float z   = fmaf(rs, aS[r] - mu * Uc, Vc);
      zw[r] = z > 0.f ? z : 0.f;
    }
    if (m < 4){
      sRed[wv][32 + (4 * g + 0) * 4 + m] = zw[0];
      sRed[wv][32 + (4 * g + 1) * 4 + m] = zw[1];
      sRed[wv][32 + (4 * g + 2) * 4 + m] = zw[2];
      sRed[wv][32 + (4 * g + 3) * 4 + m] = zw[3];
    }
    f32x4 z4 = *(const f32x4*)&sRed[wv][32 + m * 4];

    // ---- update: h += [W2|b2]^T [z|1]
    union { u32 u[4]; short8 s; } bz;
    bz.u[0] = (g == 0) ? pk(z4[1], z4[0]) : 0u;
    bz.u[1] = (g == 0) ? pk(z4[3], z4[2]) : 0u;
    bz.u[2] = (g == 0) ? 0x00003F80u : 0u;
    bz.u[3] = 0u;

    const u16* ab = (g == 0) ? (sAp + m * 8) : &sZ[0];
    const int ainc = (g == 0) ? 128 : 0;
    #pragma unroll
    for (int t2 = 0; t2 < 32; t2++){
      short8 aw = *(const short8*)(ab + t2 * ainc);
      hv[t2 >> 1][t2 & 1] =
        __builtin_amdgcn_mfma_f32_16x16x32_bf16(aw, bz.s, hv[t2 >> 1][t2 & 1], 0, 0, 0);
    }

    __syncthreads();
    mbuf ^= 1;
  }

  // ================= phase C: out = h @ W_head + b_head ===================
  u32 hpk[16][4];
  #pragma unroll
  for (int c = 0; c < 16; c++){
    hpk[c][0] = pkr(hv[c][0][1], hv[c][0][0]);
    hpk[c][1] = pkr(hv[c][0][3], hv[c][0][2]);
    hpk[c][2] = pkr(hv[c][1][1], hv[c][1][0]);
    hpk[c][3] = pkr(hv[c][1][3], hv[c][1][3]);
    hpk[c][3] = pkr(hv[c][1][3], hv[c][1][2]);
  }

  f32x4 acc[32];
  #pragma unroll
  for (int nt = 0; nt < 32; nt++) acc[nt] = (f32x4)0.f;

  // tile t lives in buf (t+1)&1 (t0 staged into buf1 during mid d==7)
  #pragma unroll
  for (int t = 0; t < 16; t++){
    if (t < 15) stageT(Wt_hd3, t + 1, t & 1);
    union { u32 u[4]; short8 s; } bz;
    bz.u[0] = hpk[t][0]; bz.u[1] = hpk[t][1];
    bz.u[2] = hpk[t][2]; bz.u[3] = hpk[t][3];
    const char* base = LT + (((t + 1) & 1) * 32768) + afoff;
    #pragma unroll
    for (int nt = 0; nt < 32; nt++){
      short8 aw = *(const short8*)(base + nt * 1024);
      acc[nt] = __builtin_amdgcn_mfma_f32_16x16x32_bf16(aw, bz.s, acc[nt], 0, 0, 0);
    }
    __syncthreads();
  }

  float* op = out + row * 512 + g * 4;
  #pragma unroll
  for (int nt = 0; nt < 32; nt++){
    f32x4 bh = *(const f32x4*)(b_head + nt * 16 + g * 4);
    f32x4 v;
    #pragma unroll
    for (int r = 0; r < 4; r++) v[r] = acc[nt][r] + bh[r];
    *(f32x4*)(op + nt * 16) = v;
  }
}

// ---------------------------------------------------------------------------
extern "C" void kernel_launch(void* const* d_in, const int* in_sizes, int n_in,
                              void* d_out, int out_size, void* d_ws, size_t ws_size,
                              hipStream_t stream)
{
  const float* x      = (const float*)d_in[0];
  const float* W_in   = (const float*)d_in[1];
  const float* b_in   = (const float*)d_in[2];
  const float* ln_g   = (const float*)d_in[3];
  const float* ln_b   = (const float*)d_in[4];
  const float* W1     = (const float*)d_in[5];
  const float* b1     = (const float*)d_in[6];
  const float* W2     = (const float*)d_in[7];
  const float* b2     = (const float*)d_in[8];
  const float* W_head = (const float*)d_in[9];
  const float* b_head = (const float*)d_in[10];
  float* out = (float*)d_out;
  const int B = in_sizes[0] / 512;

  char* ws = (char*)d_ws;
  u16*   Wt_in3 = (u16*)ws;                 // 262144
  u16*   Wt_hd3 = Wt_in3 + 262144;          // 262144
  u16*   gw1f   = Wt_hd3 + 262144;          // 20480
  u16*   updA   = gw1f + 20480;             // 32768
  float* Up     = (float*)(updA + 32768);   // 32
  float* Vp     = Up + 32;                  // 32

  prep_k<<<2256, 256, 0, stream>>>(W_in, W_head, ln_g, W1, W2, b2, Wt_in3, Wt_hd3, gw1f, updA);
  uv_k<<<32, 64, 0, stream>>>(ln_g, ln_b, W1, b1, Up, Vp);
  fused_k<<<B / 64, 256, 0, stream>>>(x, Wt_in3, b_in, Wt_hd3, b_head, gw1f, updA, Up, Vp, out);
}

// Round 6
// 397.356 us; speedup vs baseline: 5.4131x; 1.1903x over previous
//
#include <hip/hip_runtime.h>
#include <cstdint>

typedef unsigned short u16;
typedef unsigned int   u32;
typedef float  f32x4  __attribute__((ext_vector_type(4)));
typedef short  short8 __attribute__((ext_vector_type(8)));

__device__ inline float bf2f(u16 b){ u32 u=((u32)b)<<16; float f; __builtin_memcpy(&f,&u,4); return f; }
__device__ inline u16 f2bf(float f){ u32 u; __builtin_memcpy(&u,&f,4); u32 r=u+0x7FFFu+((u>>16)&1u); return (u16)(r>>16); }
// truncating pack (exact when inputs already bf16-valued)
__device__ inline u32 pk(float hi, float lo){ u32 a,b; __builtin_memcpy(&a,&hi,4); __builtin_memcpy(&b,&lo,4); return __builtin_amdgcn_perm(a,b,0x07060302u); }
// RNE pack
__device__ inline u32 pkr(float hi, float lo){ return (u32)f2bf(lo) | ((u32)f2bf(hi)<<16); }
__device__ inline void gload_lds16(const void* g, void* l){
  __builtin_amdgcn_global_load_lds((const __attribute__((address_space(1))) unsigned int*)g,
                                   (__attribute__((address_space(3))) unsigned int*)l, 16, 0, 0);
}

// ---------------------------------------------------------------------------
// prep (unchanged from round 5 — staged-order weight images):
//  tile t (of 16, 32 k each) = 16384 u16 = 256 lines x 128B.
//  decode of u16 offset o: line=o>>6, w=o&63, slot=w>>3, i=w&7,
//    c8 = slot ^ (line&7), n = 2*line + (c8>>2), g = c8&3.
//  Wt_in3 value = bf16(W_in[k][n]),  k = t*32 + g*8 + i      (linear k)
//  Wt_hd3 value = bf16(W_head[k][n]), k = t*32 + sigma(g,i)  (sigma-permuted)
//  gw1f: S-MFMA B-frags [8d][16c][4g][5col][8i] (2560/depth)
//  updA: update A-frags [8d][32t][16m][8sl]     (4096/depth)
// ---------------------------------------------------------------------------
__global__ __launch_bounds__(256) void prep_k(
    const float* __restrict__ W_in, const float* __restrict__ W_head,
    const float* __restrict__ ln_g, const float* __restrict__ W1,
    const float* __restrict__ W2, const float* __restrict__ b2,
    u16* __restrict__ Wt_in3, u16* __restrict__ Wt_hd3,
    u16* __restrict__ gw1f, u16* __restrict__ updA)
{
  int idx = blockIdx.x * 256 + threadIdx.x;
  if (idx < 524288){
    int which = idx >> 18;            // 0: W_in, 1: W_head
    int q = idx & 262143;
    int t = q >> 14, o = q & 16383;
    int line = o >> 6, w = o & 63, slot = w >> 3, i = w & 7;
    int c8 = slot ^ (line & 7);
    int n = 2 * line + (c8 >> 2);
    int g = c8 & 3;
    if (which == 0){
      int k = t * 32 + g * 8 + i;
      Wt_in3[q] = f2bf(W_in[k * 512 + n]);
    } else {
      int k = t * 32 + (i < 4 ? 4 * g + i : 12 + 4 * g + i);
      Wt_hd3[q] = f2bf(W_head[k * 512 + n]);
    }
  } else if (idx < 544768){
    int q = idx - 524288;                 // 8*2560
    int d = q / 2560, r = q % 2560;
    int c = r / 160, r2 = r % 160;
    int g = r2 / 40, r3 = r2 % 40;
    int col = r3 >> 3, i = r3 & 7;
    int k = 32 * c + (i < 4 ? 4 * g + i : 12 + 4 * g + i);
    u16 v;
    if (col == 4) v = 0x3F80u;
    else          v = f2bf(ln_g[d * 512 + k] * W1[(d * 512 + k) * 4 + col]);
    gw1f[q] = v;
  } else if (idx < 577536){
    int q = idx - 544768;                 // 8*4096
    int d = q >> 12, r = q & 4095;
    int t = r >> 7, r2 = r & 127;
    int m = r2 >> 3, sl = r2 & 7;
    int k = 16 * t + m;
    u16 v = 0;
    if (sl < 4)       v = f2bf(W2[(d * 4 + sl) * 512 + k]);
    else if (sl == 4) v = f2bf(b2[d * 512 + k]);
    updA[q] = v;
  }
}

// U[d][e] = sum_k bf16(g*W1); V = sum ln_b*W1 + b1
__global__ __launch_bounds__(64) void uv_k(
    const float* __restrict__ ln_g, const float* __restrict__ ln_b,
    const float* __restrict__ W1, const float* __restrict__ b1,
    float* __restrict__ U, float* __restrict__ V)
{
  int d = blockIdx.x >> 2, e = blockIdx.x & 3;
  int lane = threadIdx.x;
  float u = 0.f, v = 0.f;
  for (int k = lane; k < 512; k += 64){
    float w = W1[(d * 512 + k) * 4 + e];
    u += bf2f(f2bf(ln_g[d * 512 + k] * w));
    v += ln_b[d * 512 + k] * w;
  }
  for (int m = 1; m < 64; m <<= 1){ u += __shfl_xor(u, m); v += __shfl_xor(v, m); }
  if (lane == 0){ U[d * 4 + e] = u; V[d * 4 + e] = v + b1[d * 4 + e]; }
}

// ---------------------------------------------------------------------------
// fused v2: 128 rows/block, 8 waves (512 thr), n-split decomposition.
// wave wv: nq = wv&3 (n-quarter / k-slice / out-quarter), rh = wv>>2 (row half).
// hv[q][c2][half][r] = h[row = rh*64+q*16+m][k = nq*128 + c2*32 + half*16 + 4g+r]
// Phase A: x direct from global (coalesced 128B per 16-row group), weight tiles
//   staged 32KB dbuf, each wave reads only its 8 n-frags (4x fewer LDS reads).
// Mid: per-depth cross-wave (4 nq-slices) partial reduce of S/sum/ssq via LDS,
//   z broadcast, per-slice update MFMAs. Same MFMA idioms as round 5.
// Phase C: k-chunk owner broadcasts its packed-bf16 h frags via small LDS hx
//   buffer; each wave accumulates its out-quarter with full-k chain (same
//   order as round 5). Wt_hd3 unchanged.
// ---------------------------------------------------------------------------
__global__ __launch_bounds__(512, 2) void fused_k(
    const float* __restrict__ x, const u16* __restrict__ Wt_in3,
    const float* __restrict__ b_in, const u16* __restrict__ Wt_hd3,
    const float* __restrict__ b_head, const u16* __restrict__ gw1f,
    const u16* __restrict__ updA, const float* __restrict__ U,
    const float* __restrict__ V, float* __restrict__ out)
{
  __shared__ __align__(16) char LT[96544];
  // regions: [0,64K) A/C weight dbuf; [32K,64K) mid dbuf (2x16K);
  // [64K,80K) hx h-broadcast (2par x 2rh x 4KB); [80K..) sS partials, zbuf, sUV, sZ
  constexpr int HX = 65536, SSo = 81920, ZBo = 94208, UVo = 96256, SZo = 96512;
  float* sSf = (float*)(LT + SSo);
  float* zbf = (float*)(LT + ZBo);
  float* sUV = (float*)(LT + UVo);
  u16*   sZ  = (u16*)(LT + SZo);

  const int tid  = threadIdx.x;
  const int wv   = tid >> 6;
  const int lane = tid & 63;
  const int m    = lane & 15;
  const int g    = lane >> 4;
  const int nq   = wv & 3;
  const int rh   = wv >> 2;
  const size_t rowbase = (size_t)blockIdx.x * 128 + rh * 64;

  if (tid < 32) sUV[tid] = U[tid];
  else if (tid < 64) sUV[tid] = V[tid - 32];
  if (tid >= 64 && tid < 72) sZ[tid - 64] = 0;

  auto stageA = [&](const u16* W, int t, char* dst){
    const char* src = (const char*)(W + t * 16384) + tid * 16;
    char* d2 = dst + tid * 16;
    #pragma unroll
    for (int j = 0; j < 4; ++j)
      gload_lds16(src + j * 8192, d2 + j * 8192);
  };
  auto stageM = [&](int d, int bf2){
    char* dsg = LT + 32768 + bf2 * 16384;
    if (tid < 320)
      gload_lds16((const char*)gw1f + d * 5120 + tid * 16, dsg + tid * 16);
    gload_lds16((const char*)updA + d * 8192 + tid * 16, dsg + 5120 + tid * 16);
  };

  auto mkfrag = [&](f32x4 a, f32x4 b)->short8{     // RNE
    union{u32 u[4]; short8 s;} t;
    t.u[0]=pkr(a[1],a[0]); t.u[1]=pkr(a[3],a[2]);
    t.u[2]=pkr(b[1],b[0]); t.u[3]=pkr(b[3],b[2]);
    return t.s;
  };
  auto mkfragT = [&](f32x4 a, f32x4 b)->short8{    // trunc (h already bf16-valued or matches r5)
    union{u32 u[4]; short8 s;} t;
    t.u[0]=pk(a[1],a[0]); t.u[1]=pk(a[3],a[2]);
    t.u[2]=pk(b[1],b[0]); t.u[3]=pk(b[3],b[2]);
    return t.s;
  };

  // A-frag byte base inside a staged tile (proven conflict-light pattern)
  const int afoff = (m >> 1) * 128 + (((((m & 1) << 2) | g) ^ ((m >> 1) & 7)) << 4);

  // ================= phase A: h = relu(x @ W_in + b_in) =================
  f32x4 hv[4][4][2];
  #pragma unroll
  for (int q = 0; q < 4; ++q)
    #pragma unroll
    for (int c2 = 0; c2 < 4; ++c2){ hv[q][c2][0] = (f32x4)0.f; hv[q][c2][1] = (f32x4)0.f; }

  const float* xbase = x + (rowbase + m) * 512 + g * 8;
  short8 bq[2][4];
  {
    f32x4 x0[4][2];
    #pragma unroll
    for (int q = 0; q < 4; ++q){
      x0[q][0] = *(const f32x4*)(xbase + q * 8192);
      x0[q][1] = *(const f32x4*)(xbase + q * 8192 + 4);
    }
    stageA(Wt_in3, 0, LT);
    #pragma unroll
    for (int q = 0; q < 4; ++q) bq[0][q] = mkfrag(x0[q][0], x0[q][1]);
  }
  __syncthreads();

  #pragma unroll 2
  for (int t = 0; t < 16; ++t){
    const int pb = t & 1;
    if (t < 15) stageA(Wt_in3, t + 1, LT + ((t + 1) & 1) * 32768);
    f32x4 xn[4][2];
    if (t < 15){
      #pragma unroll
      for (int q = 0; q < 4; ++q){
        xn[q][0] = *(const f32x4*)(xbase + q * 8192 + (t + 1) * 32);
        xn[q][1] = *(const f32x4*)(xbase + q * 8192 + (t + 1) * 32 + 4);
      }
    }
    const char* wb = LT + pb * 32768 + nq * 8192 + afoff;
    #pragma unroll
    for (int f = 0; f < 8; ++f){
      short8 aw = *(const short8*)(wb + f * 1024);
      #pragma unroll
      for (int q = 0; q < 4; ++q)
        hv[q][f >> 1][f & 1] =
          __builtin_amdgcn_mfma_f32_16x16x32_bf16(aw, bq[pb][q], hv[q][f >> 1][f & 1], 0, 0, 0);
    }
    if (t < 15){
      #pragma unroll
      for (int q = 0; q < 4; ++q) bq[pb ^ 1][q] = mkfrag(xn[q][0], xn[q][1]);
    }
    __syncthreads();
  }

  // epilogue: +bias, relu, round to bf16 values
  #pragma unroll
  for (int q = 0; q < 4; ++q)
    #pragma unroll
    for (int c2 = 0; c2 < 4; ++c2)
      #pragma unroll
      for (int hf = 0; hf < 2; ++hf){
        f32x4 bi = *(const f32x4*)(b_in + nq * 128 + c2 * 32 + hf * 16 + g * 4);
        #pragma unroll
        for (int r = 0; r < 4; ++r){
          float v = hv[q][c2][hf][r] + bi[r];
          v = v > 0.f ? v : 0.f;
          hv[q][c2][hf][r] = bf2f(f2bf(v));
        }
      }

  // ================= mid: 8 residual MLP blocks (n-split) =================
  stageM(0, 0);
  __syncthreads();
  int buf = 0;
  #pragma unroll 1
  for (int d = 0; d < 8; ++d){
    if (d < 7) stageM(d + 1, buf ^ 1);
    else       stageA(Wt_hd3, 0, LT);          // prefetch C chunk 0

    const u16* sGp = (const u16*)(LT + 32768 + buf * 16384);
    const u16* sAp = sGp + 2560;

    // ---- per-slice S + sum(ones col) + Gram(sumsq), 4 row-groups
    const u16* gb = (m < 5) ? (sGp + nq * 640 + g * 40 + m * 8) : sZ;
    const int gstep = (m < 5) ? 160 : 0;
    f32x4 aS[4], aG[4];
    #pragma unroll
    for (int q = 0; q < 4; ++q){ aS[q] = (f32x4)0.f; aG[q] = (f32x4)0.f; }
    #pragma unroll
    for (int c2 = 0; c2 < 4; ++c2){
      short8 bf = *(const short8*)(gb + c2 * gstep);
      #pragma unroll
      for (int q = 0; q < 4; ++q){
        short8 af = mkfragT(hv[q][c2][0], hv[q][c2][1]);
        aS[q] = __builtin_amdgcn_mfma_f32_16x16x32_bf16(af, bf, aS[q], 0, 0, 0);
        aG[q] = __builtin_amdgcn_mfma_f32_16x16x32_bf16(af, af, aG[q], 0, 0, 0);
      }
    }

    // ---- write per-slice partials: [rh][q][nq][e=0..5][16 batch]
    #pragma unroll
    for (int q = 0; q < 4; ++q){
      if (m < 5)
        *(f32x4*)(sSf + (((rh * 4 + q) * 4 + nq) * 6 + m) * 16 + 4 * g) = aS[q];
      if ((m >> 2) == g)
        sSf[(((rh * 4 + q) * 4 + nq) * 6 + 5) * 16 + m] = aG[q][m & 3];
    }
    __syncthreads();

    // ---- z for all 128 rows (threads 0..127)
    if (tid < 128){
      int rh2 = tid >> 6, rl = tid & 63, q2 = rl >> 4, b = rl & 15;
      float S0 = 0.f, S1 = 0.f, S2 = 0.f, S3 = 0.f, sm = 0.f, sq = 0.f;
      #pragma unroll
      for (int nn = 0; nn < 4; ++nn){
        const float* pp = sSf + (((rh2 * 4 + q2) * 4 + nn) * 6) * 16 + b;
        S0 += pp[0]; S1 += pp[16]; S2 += pp[32]; S3 += pp[48];
        sm += pp[64]; sq += pp[80];
      }
      float mu  = sm * (1.f / 512.f);
      float var = sq * (1.f / 512.f) - mu * mu;
      float rs  = rsqrtf(var + 1e-5f);
      f32x4 zz;
      float z0 = fmaf(rs, S0 - mu * sUV[d * 4 + 0], sUV[32 + d * 4 + 0]);
      float z1 = fmaf(rs, S1 - mu * sUV[d * 4 + 1], sUV[32 + d * 4 + 1]);
      float z2 = fmaf(rs, S2 - mu * sUV[d * 4 + 2], sUV[32 + d * 4 + 2]);
      float z3 = fmaf(rs, S3 - mu * sUV[d * 4 + 3], sUV[32 + d * 4 + 3]);
      zz[0] = z0 > 0.f ? z0 : 0.f;
      zz[1] = z1 > 0.f ? z1 : 0.f;
      zz[2] = z2 > 0.f ? z2 : 0.f;
      zz[3] = z3 > 0.f ? z3 : 0.f;
      *(f32x4*)(zbf + tid * 4) = zz;
    }
    __syncthreads();

    // ---- update: h += [W2|b2]^T [z|1] on own k-slice
    #pragma unroll
    for (int q = 0; q < 4; ++q){
      f32x4 z4 = *(const f32x4*)(zbf + (rh * 64 + q * 16 + m) * 4);
      union{u32 u[4]; short8 s;} bz;
      bz.u[0] = (g == 0) ? pk(z4[1], z4[0]) : 0u;
      bz.u[1] = (g == 0) ? pk(z4[3], z4[2]) : 0u;
      bz.u[2] = (g == 0) ? 0x00003F80u : 0u;
      bz.u[3] = 0u;
      const u16* ab = (g == 0) ? (sAp + nq * 1024 + m * 8) : sZ;
      const int ainc = (g == 0) ? 128 : 0;
      #pragma unroll
      for (int t2 = 0; t2 < 8; ++t2){
        short8 aw = *(const short8*)(ab + t2 * ainc);
        hv[q][t2 >> 1][t2 & 1] =
          __builtin_amdgcn_mfma_f32_16x16x32_bf16(aw, bz.s, hv[q][t2 >> 1][t2 & 1], 0, 0, 0);
      }
    }
    __syncthreads();
    buf ^= 1;
  }

  // ================= phase C: out = h @ W_head + b_head ===================
  // pack h (RNE — pipeline's final h rounding, matches round 5)
  short8 p[4][4];
  #pragma unroll
  for (int q = 0; q < 4; ++q)
    #pragma unroll
    for (int c2 = 0; c2 < 4; ++c2)
      p[q][c2] = mkfrag(hv[q][c2][0], hv[q][c2][1]);

  f32x4 acc[4][8];
  #pragma unroll
  for (int q = 0; q < 4; ++q)
    #pragma unroll
    for (int of = 0; of < 8; ++of) acc[q][of] = (f32x4)0.f;

  // broadcast chunk 0 (owner nq==0)
  if (nq == 0){
    #pragma unroll
    for (int q = 0; q < 4; ++q)
      *(short8*)(LT + HX + rh * 4096 + (q * 64 + m * 4 + g) * 16) = p[q][0];
  }
  __syncthreads();

  #pragma unroll 4
  for (int c = 0; c < 16; ++c){
    if (c < 15){
      stageA(Wt_hd3, c + 1, LT + ((c + 1) & 1) * 32768);
      if (nq == ((c + 1) >> 2)){
        #pragma unroll
        for (int q = 0; q < 4; ++q)
          *(short8*)(LT + HX + ((c + 1) & 1) * 8192 + rh * 4096 + (q * 64 + m * 4 + g) * 16)
            = p[q][(c + 1) & 3];
      }
    }
    const char* hxb = LT + HX + (c & 1) * 8192 + rh * 4096 + (m * 4 + g) * 16;
    short8 bh[4];
    #pragma unroll
    for (int q = 0; q < 4; ++q) bh[q] = *(const short8*)(hxb + q * 1024);
    const char* wb = LT + (c & 1) * 32768 + nq * 8192 + afoff;
    #pragma unroll
    for (int of = 0; of < 8; ++of){
      short8 aw = *(const short8*)(wb + of * 1024);
      #pragma unroll
      for (int q = 0; q < 4; ++q)
        acc[q][of] = __builtin_amdgcn_mfma_f32_16x16x32_bf16(aw, bh[q], acc[q][of], 0, 0, 0);
    }
    __syncthreads();
  }

  // epilogue: +bias, store
  #pragma unroll
  for (int q = 0; q < 4; ++q)
    #pragma unroll
    for (int of = 0; of < 8; ++of){
      f32x4 bhd = *(const f32x4*)(b_head + nq * 128 + of * 16 + g * 4);
      f32x4 v;
      #pragma unroll
      for (int r = 0; r < 4; ++r) v[r] = acc[q][of][r] + bhd[r];
      *(f32x4*)(out + (rowbase + q * 16 + m) * 512 + nq * 128 + of * 16 + g * 4) = v;
    }
}

// ---------------------------------------------------------------------------
extern "C" void kernel_launch(void* const* d_in, const int* in_sizes, int n_in,
                              void* d_out, int out_size, void* d_ws, size_t ws_size,
                              hipStream_t stream)
{
  const float* x      = (const float*)d_in[0];
  const float* W_in   = (const float*)d_in[1];
  const float* b_in   = (const float*)d_in[2];
  const float* ln_g   = (const float*)d_in[3];
  const float* ln_b   = (const float*)d_in[4];
  const float* W1     = (const float*)d_in[5];
  const float* b1     = (const float*)d_in[6];
  const float* W2     = (const float*)d_in[7];
  const float* b2     = (const float*)d_in[8];
  const float* W_head = (const float*)d_in[9];
  const float* b_head = (const float*)d_in[10];
  float* out = (float*)d_out;
  const int B = in_sizes[0] / 512;

  char* ws = (char*)d_ws;
  u16*   Wt_in3 = (u16*)ws;                 // 262144
  u16*   Wt_hd3 = Wt_in3 + 262144;          // 262144
  u16*   gw1f   = Wt_hd3 + 262144;          // 20480
  u16*   updA   = gw1f + 20480;             // 32768
  float* Up     = (float*)(updA + 32768);   // 32
  float* Vp     = Up + 32;                  // 32

  prep_k<<<2256, 256, 0, stream>>>(W_in, W_head, ln_g, W1, W2, b2, Wt_in3, Wt_hd3, gw1f, updA);
  uv_k<<<32, 64, 0, stream>>>(ln_g, ln_b, W1, b1, Up, Vp);
  fused_k<<<B / 128, 512, 0, stream>>>(x, Wt_in3, b_in, Wt_hd3, b_head, gw1f, updA, Up, Vp, out);
}